// Round 14
// baseline (131.078 us; speedup 1.0000x reference)
//
#include <hip/hip_runtime.h>
#include <hip/hip_bf16.h>
#include <stdint.h>

#define B_    2
#define S_    2048
#define D_    1024
#define H_    16
#define DH_   64
#define MTOT  (B_*S_)     // 4096
#define NQKV  (3*D_)      // 3072

typedef __attribute__((ext_vector_type(8))) short  bf16x8;
typedef __attribute__((ext_vector_type(4))) short  bf16x4;
typedef __attribute__((ext_vector_type(4))) float  f32x4;
typedef __attribute__((ext_vector_type(8))) unsigned short u16x8;
typedef unsigned short ushort_t;

__device__ __forceinline__ ushort_t f2bf(float f) {
  union { float f; unsigned int i; } v; v.f = f;
  unsigned int r = v.i + 0x7FFF + ((v.i >> 16) & 1);
  return (ushort_t)(r >> 16);
}

__device__ __forceinline__ unsigned cvt_pk_bf16(float lo, float hi) {
  unsigned r;
  asm("v_cvt_pk_bf16_f32 %0, %1, %2" : "=v"(r) : "v"(lo), "v"(hi));
  return r;
}

__device__ __forceinline__ float fexp2(float x) {
  float r;
  asm("v_exp_f32 %0, %1" : "=v"(r) : "v"(x));
  return r;
}

// K=16 bf16 MFMA: builtin name differs across ROCm versions; chain with asm fallback.
#if __has_builtin(__builtin_amdgcn_mfma_f32_16x16x16_bf16)
__device__ __forceinline__ f32x4 mfma16(bf16x4 a, bf16x4 b, f32x4 c) {
  return __builtin_amdgcn_mfma_f32_16x16x16_bf16(a, b, c, 0, 0, 0);
}
#elif __has_builtin(__builtin_amdgcn_mfma_f32_16x16x16bf16_1k)
__device__ __forceinline__ f32x4 mfma16(bf16x4 a, bf16x4 b, f32x4 c) {
  return __builtin_amdgcn_mfma_f32_16x16x16bf16_1k(a, b, c, 0, 0, 0);
}
#else
__device__ __forceinline__ f32x4 mfma16(bf16x4 a, bf16x4 b, f32x4 c) {
  asm volatile("v_mfma_f32_16x16x16_bf16 %0, %1, %2, %0"
               : "+v"(c) : "v"(a), "v"(b));
  return c;
}
#endif

__device__ __forceinline__ void gl_lds16(const ushort_t* g, ushort_t* l) {
  __builtin_amdgcn_global_load_lds(
      (const __attribute__((address_space(1))) unsigned int*)g,
      (__attribute__((address_space(3))) unsigned int*)l, 16, 0, 0);
}

// ---------------- fused fp32 -> bf16 conversion (x, Wi, Wo) ----------------
#define CVN1 (MTOT*D_/8)
#define CVN2 (NQKV*D_/8)
#define CVN3 (D_*D_/8)
__global__ __launch_bounds__(256) void cvt_all(
    const float* __restrict__ x, const float* __restrict__ Wi, const float* __restrict__ Wo,
    ushort_t* __restrict__ xb, ushort_t* __restrict__ Wib, ushort_t* __restrict__ Wob) {
  int i = blockIdx.x * blockDim.x + threadIdx.x;
  const float* src; ushort_t* dst; int k;
  if (i < CVN1)            { src = x;  dst = xb;  k = i; }
  else if (i < CVN1+CVN2)  { src = Wi; dst = Wib; k = i - CVN1; }
  else                     { src = Wo; dst = Wob; k = i - CVN1 - CVN2; }
  const float4* s4 = (const float4*)src;
  float4 a = s4[2*k], b = s4[2*k+1];
  u16x8 o;
  o[0]=f2bf(a.x); o[1]=f2bf(a.y); o[2]=f2bf(a.z); o[3]=f2bf(a.w);
  o[4]=f2bf(b.x); o[5]=f2bf(b.y); o[6]=f2bf(b.z); o[7]=f2bf(b.w);
  ((u16x8*)dst)[k] = o;
}

// ---------------- QKV GEMM: qkv = x @ Wi^T + bi ----------------
#define BKQ 32
#define BKO 64
// scale folded into q: 1/sqrt(64) * log2(e)  (exp2-domain softmax)
#define QSCALE 0.18033688011112042f
__global__ __launch_bounds__(256) void gemm_qkv(
    const ushort_t* __restrict__ Abf, const ushort_t* __restrict__ Bbf,
    const float* __restrict__ bias,
    ushort_t* __restrict__ qb, ushort_t* __restrict__ kb, ushort_t* __restrict__ vb) {
  __shared__ __align__(16) ushort_t Al[2][128*BKQ];
  __shared__ __align__(16) ushort_t Bl[2][128*BKQ];
  int tid = threadIdx.x;
  int w = tid >> 6, lane = tid & 63;
  int wrow = (w >> 1) * 64, wcol = (w & 1) * 64;
  int bid = blockIdx.y * 24 + blockIdx.x;
  int swz = (bid & 7) * 96 + (bid >> 3);
  int m0 = (swz / 24) * 128, n0 = (swz % 24) * 128;
  const int K = D_;
  const int nt = K / BKQ;

  auto stageg = [&](int t, int buf) {
    int k0 = t * BKQ;
    #pragma unroll
    for (int it = 0; it < 2; ++it) {
      int c = it*256 + tid;
      int row = c >> 2, cc = c & 3;
      int lbase = (it*256 + w*64) * 8;
      gl_lds16(Abf + (size_t)(m0+row)*K + k0 + cc*8, &Al[buf][lbase]);
      gl_lds16(Bbf + (size_t)(n0+row)*K + k0 + cc*8, &Bl[buf][lbase]);
    }
  };

  f32x4 zero = {0.f, 0.f, 0.f, 0.f};
  f32x4 acc[4][4];
  for (int i=0;i<4;i++) for (int j=0;j<4;j++) acc[i][j] = zero;

  stageg(0, 0);
  asm volatile("s_waitcnt vmcnt(0)" ::: "memory");
  __builtin_amdgcn_s_barrier();

  for (int t = 0; t < nt; ++t) {
    int cur = t & 1;
    if (t + 1 < nt) stageg(t + 1, cur ^ 1);
    int kof = (lane >> 4) * 8;
    bf16x8 af[4], bfr[4];
    for (int i=0;i<4;i++) af[i]  = *(const bf16x8*)(&Al[cur][(wrow + i*16 + (lane&15))*BKQ + kof]);
    for (int j=0;j<4;j++) bfr[j] = *(const bf16x8*)(&Bl[cur][(wcol + j*16 + (lane&15))*BKQ + kof]);
    for (int i=0;i<4;i++)
      for (int j=0;j<4;j++)
        acc[i][j] = __builtin_amdgcn_mfma_f32_16x16x32_bf16(af[i], bfr[j], acc[i][j], 0, 0, 0);
    asm volatile("s_waitcnt vmcnt(0)" ::: "memory");
    __builtin_amdgcn_s_barrier();
  }
  for (int i=0;i<4;i++)
    for (int j=0;j<4;j++)
      for (int r=0;r<4;r++) {
        int gm = m0 + wrow + i*16 + (lane>>4)*4 + r;
        int gn = n0 + wcol + j*16 + (lane&15);
        float v = acc[i][j][r] + bias[gn];
        int b = gm >> 11, s = gm & (S_-1);
        int sect = gn >> 10, hn = gn & (D_-1);
        int hh = hn >> 6, d = hn & 63;
        size_t idx = (((size_t)(b*H_ + hh))*S_ + s)*DH_ + d;
        if (sect == 0) v *= QSCALE;
        ushort_t val = f2bf(v);
        if (sect == 0) qb[idx] = val;
        else if (sect == 1) kb[idx] = val;
        else vb[idx] = val;
      }
}

// ---------------- V transpose: [BH][S][DH] -> [BH][DH][S] ----------------
__global__ __launch_bounds__(256) void transpose_v(
    const ushort_t* __restrict__ vb, ushort_t* __restrict__ vtb) {
  __shared__ ushort_t T[64*72];
  int bh = blockIdx.y;
  int s0 = blockIdx.x * 64;
  int tid = threadIdx.x;
  const ushort_t* src = vb + (size_t)bh * S_ * DH_;
  ushort_t* dst = vtb + (size_t)bh * DH_ * S_;
  for (int it = 0; it < 2; ++it) {
    int c = it*256 + tid;
    int row = c >> 3, cc = c & 7;
    *(uint4*)&T[row*72 + cc*8] = *(const uint4*)(src + (size_t)(s0+row)*DH_ + cc*8);
  }
  __syncthreads();
  for (int it = 0; it < 2; ++it) {
    int c = it*256 + tid;
    int d = c >> 3, sc = c & 7;
    u16x8 o;
    #pragma unroll
    for (int e = 0; e < 8; ++e) o[e] = T[(sc*8+e)*72 + d];
    *(u16x8*)(dst + (size_t)d*S_ + s0 + sc*8) = o;
  }
}

// ---------------- flash attention v10 ----------------
// 1024 blocks x 2 waves (128 thr); 64-row q-blocks, 32 q-rows/wave (two
// 16-row C-tiles) -> K/V fragments hoisted to regs and shared across both
// tiles: DS reads per q-row HALVED. Same grid map / LDS layout / address
// patterns as v9 (boustrophedon, XCD-grouped bh, 2-buffer KV).
#define KVB 64
#define DTHR 8.0f
__global__ __launch_bounds__(128) void attn_fwd(
    const ushort_t* __restrict__ qb, const ushort_t* __restrict__ kb,
    const ushort_t* __restrict__ vtb, ushort_t* __restrict__ attnb,
    const int* __restrict__ causal) {
  int wg = blockIdx.x;                  // 0..1023
  int xcd = wg & 7;
  int j = wg >> 3;                      // 0..127 per-XCD dispatch sequence
  int v = j >> 5;                       // visit 0..3
  int u = j & 31;                       // CU slot within XCD
  int a = u >> 2;                       // qblk subgroup 0..7
  int qi = v*8 + ((v & 1) ? (7 - a) : a);   // boustrophedon: per-CU sums equal
  int qblk = 31 - qi;
  int bh = (u & 3) * 8 + xcd;           // 4 bh per XCD -> KV L2-resident
  int b = bh >> 4, h = bh & 15;
  int tid = threadIdx.x, w = tid >> 6, lane = tid & 63;
  int g = lane >> 4, q16 = lane & 15;
  const ushort_t* qh  = qb  + (size_t)bh * S_ * DH_;
  const ushort_t* kh  = kb  + (size_t)bh * S_ * DH_;
  const ushort_t* vth = vtb + (size_t)bh * DH_ * S_;
  __shared__ __align__(16) ushort_t Kl[2][KVB*64];
  __shared__ __align__(16) ushort_t Vtl[2][64*KVB];
  bool use_causal = (causal[0] != 0);

  int nkv = use_causal ? (qblk + 1) : (S_/KVB);
  int qw = qblk*64 + w*32;              // wave's 32-row base

  // Q fragments for both 16-row tiles
  bf16x8 qc[2][2];
  #pragma unroll
  for (int qt=0; qt<2; ++qt)
    #pragma unroll
    for (int kk=0; kk<2; ++kk)
      qc[qt][kk] = *(const bf16x8*)(qh + (size_t)(qw + qt*16 + q16)*DH_ + kk*32 + g*8);

  // staging: 128 threads x 4 chunks each for K and Vt (src-side XOR swizzle)
  const ushort_t* kp[4]; const ushort_t* vp[4]; int ldo[4];
  #pragma unroll
  for (int k2=0;k2<4;k2++) {
    int c = tid + k2*128;
    int row = c >> 3, sw = ((c & 7) ^ (row & 7)) * 8;
    kp[k2] = kh + row*DH_ + sw;
    vp[k2] = vth + (size_t)row*S_ + sw;
    ldo[k2] = c*8;
  }
  auto stage = [&](int t, int buf) {
    size_t kadv = (size_t)(t*KVB) * DH_;
    int vadv = t*KVB;
    #pragma unroll
    for (int k2=0;k2<4;k2++) {
      gl_lds16(kp[k2] + kadv, &Kl[buf][ldo[k2]]);
      gl_lds16(vp[k2] + vadv, &Vtl[buf][ldo[k2]]);
    }
  };

  f32x4 zero = {0.f,0.f,0.f,0.f};
  f32x4 o[2][4];
  #pragma unroll
  for (int qt=0;qt<2;qt++)
    #pragma unroll
    for (int dt=0;dt<4;dt++) o[qt][dt] = zero;
  float mrun[2] = {-1e30f, -1e30f}, lrun[2] = {0.f, 0.f};

  stage(0, 0);
  asm volatile("s_waitcnt vmcnt(0)" ::: "memory");
  __builtin_amdgcn_s_barrier();

  for (int it = 0; it < nkv; ++it) {
    int cur = it & 1;
    int kvbase = it * KVB;
    if (it + 1 < nkv) stage(it + 1, cur ^ 1);   // lands during compute below

    // ---- K fragments hoisted once, shared by both q-tiles ----
    bf16x8 kf[2][4];
    #pragma unroll
    for (int kk=0;kk<2;kk++)
      #pragma unroll
      for (int j2=0;j2<4;j2++) {
        int row = j2*16 + q16;
        int slot = (kk*4 + g) ^ (row & 7);
        kf[kk][j2] = *(const bf16x8*)(&Kl[cur][row*64 + slot*8]);
      }
    // ---- QK^T both tiles: sacc[qt][j2][r] = S[kv=16j2+4g+r][q=q16] ----
    f32x4 sacc[2][4];
    #pragma unroll
    for (int qt=0;qt<2;qt++)
      #pragma unroll
      for (int j2=0;j2<4;j2++) sacc[qt][j2] = zero;
    #pragma unroll
    for (int qt=0;qt<2;qt++)
      #pragma unroll
      for (int kk=0;kk<2;kk++)
        #pragma unroll
        for (int j2=0;j2<4;j2++)
          sacc[qt][j2] = __builtin_amdgcn_mfma_f32_16x16x32_bf16(kf[kk][j2], qc[qt][kk], sacc[qt][j2], 0, 0, 0);

    // ---- per-tile mask + online softmax (exp2 domain, defer-max) ----
    bf16x4 pkv[2][4];
    #pragma unroll
    for (int qt=0;qt<2;qt++) {
      if (use_causal && kvbase + KVB - 1 > qw + qt*16) {
        int qd = qw + qt*16 + q16 - kvbase;
        #pragma unroll
        for (int j2=0;j2<4;j2++)
          #pragma unroll
          for (int r=0;r<4;r++)
            if (16*j2 + 4*g + r > qd) sacc[qt][j2][r] = -1e30f;
      }
      float m0v = fmaxf(fmaxf(sacc[qt][0][0], sacc[qt][0][1]), fmaxf(sacc[qt][0][2], sacc[qt][0][3]));
      float m1v = fmaxf(fmaxf(sacc[qt][1][0], sacc[qt][1][1]), fmaxf(sacc[qt][1][2], sacc[qt][1][3]));
      float m2v = fmaxf(fmaxf(sacc[qt][2][0], sacc[qt][2][1]), fmaxf(sacc[qt][2][2], sacc[qt][2][3]));
      float m3v = fmaxf(fmaxf(sacc[qt][3][0], sacc[qt][3][1]), fmaxf(sacc[qt][3][2], sacc[qt][3][3]));
      float mx = fmaxf(fmaxf(m0v, m1v), fmaxf(m2v, m3v));
      mx = fmaxf(mx, __shfl_xor(mx, 16, 64));
      mx = fmaxf(mx, __shfl_xor(mx, 32, 64));
      if (!__all(mx - mrun[qt] <= DTHR)) {
        float mnew = fmaxf(mrun[qt], mx);
        float alpha = fexp2(mrun[qt] - mnew);
        lrun[qt] *= alpha;
        float av0 = __shfl(alpha, 4*g + 0, 64);
        float av1 = __shfl(alpha, 4*g + 1, 64);
        float av2 = __shfl(alpha, 4*g + 2, 64);
        float av3 = __shfl(alpha, 4*g + 3, 64);
        #pragma unroll
        for (int dt=0;dt<4;dt++) {
          o[qt][dt][0] *= av0; o[qt][dt][1] *= av1; o[qt][dt][2] *= av2; o[qt][dt][3] *= av3;
        }
        mrun[qt] = mnew;
      }
      float p[4][4];
      float rs = 0.f;
      #pragma unroll
      for (int j2=0;j2<4;j2++)
        #pragma unroll
        for (int r=0;r<4;r++) {
          p[j2][r] = fexp2(sacc[qt][j2][r] - mrun[qt]);
          rs += p[j2][r];
        }
      rs += __shfl_xor(rs, 16, 64);
      rs += __shfl_xor(rs, 32, 64);
      lrun[qt] += rs;
      #pragma unroll
      for (int s=0;s<4;s++) {
        union { unsigned u2[2]; bf16x4 v2; } pk;
        pk.u2[0] = cvt_pk_bf16(p[s][0], p[s][1]);
        pk.u2[1] = cvt_pk_bf16(p[s][2], p[s][3]);
        pkv[qt][s] = pk.v2;
      }
    }
    // ---- PV: V fragments loaded once, used by both q-tiles ----
    #pragma unroll
    for (int s=0;s<4;s++) {
      int E = 16*s + 4*g;
      #pragma unroll
      for (int dt=0;dt<4;dt++) {
        int row = dt*16 + q16;
        int off = row*64 + ((E >> 3) ^ (row & 7))*8 + (E & 7);
        bf16x4 vf = *(const bf16x4*)(&Vtl[cur][off]);
        o[0][dt] = mfma16(pkv[0][s], vf, o[0][dt]);
        o[1][dt] = mfma16(pkv[1][s], vf, o[1][dt]);
      }
    }
    asm volatile("s_waitcnt vmcnt(0)" ::: "memory");
    __builtin_amdgcn_s_barrier();
  }
  // ---- epilogue (both tiles) ----
  #pragma unroll
  for (int qt=0;qt<2;qt++) {
    float li0 = 1.f / __shfl(lrun[qt], 4*g + 0, 64);
    float li1 = 1.f / __shfl(lrun[qt], 4*g + 1, 64);
    float li2 = 1.f / __shfl(lrun[qt], 4*g + 2, 64);
    float li3 = 1.f / __shfl(lrun[qt], 4*g + 3, 64);
    #pragma unroll
    for (int r=0;r<4;r++) {
      float li = (r==0)?li0:(r==1)?li1:(r==2)?li2:li3;
      int q = qw + qt*16 + 4*g + r;
      #pragma unroll
      for (int dt=0;dt<4;dt++) {
        int d = dt*16 + q16;
        attnb[((size_t)(b*S_ + q))*D_ + h*DH_ + d] = f2bf(o[qt][dt][r] * li);
      }
    }
  }
}

// ---------------- output GEMM: out = attn @ Wo^T + bo ----------------
__global__ __launch_bounds__(512) void gemm_out(
    const ushort_t* __restrict__ Abf, const ushort_t* __restrict__ Bbf,
    const float* __restrict__ bias, float* __restrict__ out) {
  __shared__ __align__(16) ushort_t Al[2][128*BKO];
  __shared__ __align__(16) ushort_t Bl[2][128*BKO];
  int tid = threadIdx.x;
  int w = tid >> 6, lane = tid & 63;
  int g = lane >> 4, q16 = lane & 15;
  int wrow = (w >> 2) * 64, wcol = (w & 3) * 32;
  int m0 = blockIdx.y * 128, n0 = blockIdx.x * 128;
  const int K = D_;
  const int nt = K / BKO;

  auto stageg = [&](int t, int buf) {
    int k0 = t * BKO;
    #pragma unroll
    for (int it = 0; it < 2; ++it) {
      int c = it*512 + tid;
      int row = c >> 3, scc = ((c & 7) ^ (row & 7)) * 8;
      gl_lds16(Abf + (size_t)(m0+row)*K + k0 + scc, &Al[buf][c*8]);
      gl_lds16(Bbf + (size_t)(n0+row)*K + k0 + scc, &Bl[buf][c*8]);
    }
  };

  f32x4 zero = {0.f,0.f,0.f,0.f};
  f32x4 acc[4][2];
  for (int i=0;i<4;i++) for (int j=0;j<2;j++) acc[i][j] = zero;

  stageg(0, 0);
  asm volatile("s_waitcnt vmcnt(0)" ::: "memory");
  __builtin_amdgcn_s_barrier();

  for (int t = 0; t < nt; ++t) {
    int cur = t & 1;
    if (t + 1 < nt) stageg(t + 1, cur ^ 1);
    #pragma unroll
    for (int kk = 0; kk < 2; ++kk) {
      bf16x8 af[4], bfr[2];
      #pragma unroll
      for (int i=0;i<4;i++) {
        int row = wrow + i*16 + q16;
        int slot = ((kk*4 + g) ^ (row & 7)) * 8;
        af[i] = *(const bf16x8*)(&Al[cur][row*BKO + slot]);
      }
      #pragma unroll
      for (int j=0;j<2;j++) {
        int row = wcol + j*16 + q16;
        int slot = ((kk*4 + g) ^ (row & 7)) * 8;
        bfr[j] = *(const bf16x8*)(&Bl[cur][row*BKO + slot]);
      }
      #pragma unroll
      for (int i=0;i<4;i++)
        #pragma unroll
        for (int j=0;j<2;j++)
          acc[i][j] = __builtin_amdgcn_mfma_f32_16x16x32_bf16(af[i], bfr[j], acc[i][j], 0, 0, 0);
    }
    asm volatile("s_waitcnt vmcnt(0)" ::: "memory");
    __builtin_amdgcn_s_barrier();
  }
  #pragma unroll
  for (int i=0;i<4;i++)
    #pragma unroll
    for (int j=0;j<2;j++)
      #pragma unroll
      for (int r=0;r<4;r++) {
        int gm = m0 + wrow + i*16 + g*4 + r;
        int gn = n0 + wcol + j*16 + q16;
        out[(size_t)gm*D_ + gn] = acc[i][j][r] + bias[gn];
      }
}

extern "C" void kernel_launch(void* const* d_in, const int* in_sizes, int n_in,
                              void* d_out, int out_size, void* d_ws, size_t ws_size,
                              hipStream_t stream) {
  const float* x  = (const float*)d_in[0];
  const float* Wi = (const float*)d_in[1];
  const float* bi = (const float*)d_in[2];
  const float* Wo = (const float*)d_in[3];
  const float* bo = (const float*)d_in[4];
  const int* causal = (const int*)d_in[5];
  float* out = (float*)d_out;

  ushort_t* xb   = (ushort_t*)d_ws;                       // 4096*1024 (reused as vtb)
  ushort_t* Wib  = xb  + (size_t)MTOT*D_;                 // 3072*1024
  ushort_t* Wob  = Wib + (size_t)NQKV*D_;                 // 1024*1024
  ushort_t* qbuf = Wob + (size_t)D_*D_;                   // 32*2048*64
  ushort_t* kbuf = qbuf + (size_t)B_*H_*S_*DH_;
  ushort_t* vbuf = kbuf + (size_t)B_*H_*S_*DH_;
  ushort_t* attnb = vbuf + (size_t)B_*H_*S_*DH_;          // 4096*1024
  ushort_t* vtb  = xb;  // xb dead after gemm_qkv; reuse for transposed V

  int ntot = CVN1 + CVN2 + CVN3;
  cvt_all<<<(ntot+255)/256, 256, 0, stream>>>(x, Wi, Wo, xb, Wib, Wob);

  gemm_qkv<<<dim3(NQKV/128, MTOT/128), 256, 0, stream>>>(xb, Wib, bi, qbuf, kbuf, vbuf);
  transpose_v<<<dim3(S_/64, B_*H_), 256, 0, stream>>>(vbuf, vtb);
  attn_fwd<<<1024, 128, 0, stream>>>(qbuf, kbuf, vtb, attnb, causal);
  gemm_out<<<dim3(D_/128, MTOT/128), 512, 0, stream>>>(attnb, Wob, bo, out);
}

// Round 15
// 119.377 us; speedup vs baseline: 1.0980x; 1.0980x over previous
//
#include <hip/hip_runtime.h>
#include <hip/hip_bf16.h>
#include <stdint.h>

#define B_    2
#define S_    2048
#define D_    1024
#define H_    16
#define DH_   64
#define MTOT  (B_*S_)     // 4096
#define NQKV  (3*D_)      // 3072

typedef __attribute__((ext_vector_type(8))) short  bf16x8;
typedef __attribute__((ext_vector_type(4))) short  bf16x4;
typedef __attribute__((ext_vector_type(4))) float  f32x4;
typedef __attribute__((ext_vector_type(8))) unsigned short u16x8;
typedef unsigned short ushort_t;

__device__ __forceinline__ ushort_t f2bf(float f) {
  union { float f; unsigned int i; } v; v.f = f;
  unsigned int r = v.i + 0x7FFF + ((v.i >> 16) & 1);
  return (ushort_t)(r >> 16);
}

__device__ __forceinline__ unsigned cvt_pk_bf16(float lo, float hi) {
  unsigned r;
  asm("v_cvt_pk_bf16_f32 %0, %1, %2" : "=v"(r) : "v"(lo), "v"(hi));
  return r;
}

__device__ __forceinline__ float fexp2(float x) {
  float r;
  asm("v_exp_f32 %0, %1" : "=v"(r) : "v"(x));
  return r;
}

// K=16 bf16 MFMA: builtin name differs across ROCm versions; chain with asm fallback.
#if __has_builtin(__builtin_amdgcn_mfma_f32_16x16x16_bf16)
__device__ __forceinline__ f32x4 mfma16(bf16x4 a, bf16x4 b, f32x4 c) {
  return __builtin_amdgcn_mfma_f32_16x16x16_bf16(a, b, c, 0, 0, 0);
}
#elif __has_builtin(__builtin_amdgcn_mfma_f32_16x16x16bf16_1k)
__device__ __forceinline__ f32x4 mfma16(bf16x4 a, bf16x4 b, f32x4 c) {
  return __builtin_amdgcn_mfma_f32_16x16x16bf16_1k(a, b, c, 0, 0, 0);
}
#else
__device__ __forceinline__ f32x4 mfma16(bf16x4 a, bf16x4 b, f32x4 c) {
  asm volatile("v_mfma_f32_16x16x16_bf16 %0, %1, %2, %0"
               : "+v"(c) : "v"(a), "v"(b));
  return c;
}
#endif

__device__ __forceinline__ void gl_lds16(const ushort_t* g, ushort_t* l) {
  __builtin_amdgcn_global_load_lds(
      (const __attribute__((address_space(1))) unsigned int*)g,
      (__attribute__((address_space(3))) unsigned int*)l, 16, 0, 0);
}

// ---------------- fused fp32 -> bf16 conversion (x, Wi, Wo) ----------------
#define CVN1 (MTOT*D_/8)
#define CVN2 (NQKV*D_/8)
#define CVN3 (D_*D_/8)
__global__ __launch_bounds__(256) void cvt_all(
    const float* __restrict__ x, const float* __restrict__ Wi, const float* __restrict__ Wo,
    ushort_t* __restrict__ xb, ushort_t* __restrict__ Wib, ushort_t* __restrict__ Wob) {
  int i = blockIdx.x * blockDim.x + threadIdx.x;
  const float* src; ushort_t* dst; int k;
  if (i < CVN1)            { src = x;  dst = xb;  k = i; }
  else if (i < CVN1+CVN2)  { src = Wi; dst = Wib; k = i - CVN1; }
  else                     { src = Wo; dst = Wob; k = i - CVN1 - CVN2; }
  const float4* s4 = (const float4*)src;
  float4 a = s4[2*k], b = s4[2*k+1];
  u16x8 o;
  o[0]=f2bf(a.x); o[1]=f2bf(a.y); o[2]=f2bf(a.z); o[3]=f2bf(a.w);
  o[4]=f2bf(b.x); o[5]=f2bf(b.y); o[6]=f2bf(b.z); o[7]=f2bf(b.w);
  ((u16x8*)dst)[k] = o;
}

// ---------------- QKV GEMM: qkv = x @ Wi^T + bi ----------------
// BK=32, 2-buffer LDS, raw-barrier pipeline; chunked XCD swizzle.
#define BKQ 32
#define BKO 64
// scale folded into q: 1/sqrt(64) * log2(e)  (exp2-domain softmax)
#define QSCALE 0.18033688011112042f
__global__ __launch_bounds__(256) void gemm_qkv(
    const ushort_t* __restrict__ Abf, const ushort_t* __restrict__ Bbf,
    const float* __restrict__ bias,
    ushort_t* __restrict__ qb, ushort_t* __restrict__ kb, ushort_t* __restrict__ vb) {
  __shared__ __align__(16) ushort_t Al[2][128*BKQ];
  __shared__ __align__(16) ushort_t Bl[2][128*BKQ];
  int tid = threadIdx.x;
  int w = tid >> 6, lane = tid & 63;
  int wrow = (w >> 1) * 64, wcol = (w & 1) * 64;
  int bid = blockIdx.y * 24 + blockIdx.x;
  int swz = (bid & 7) * 96 + (bid >> 3);
  int m0 = (swz / 24) * 128, n0 = (swz % 24) * 128;
  const int K = D_;
  const int nt = K / BKQ;

  auto stageg = [&](int t, int buf) {
    int k0 = t * BKQ;
    #pragma unroll
    for (int it = 0; it < 2; ++it) {
      int c = it*256 + tid;
      int row = c >> 2, cc = c & 3;
      int lbase = (it*256 + w*64) * 8;
      gl_lds16(Abf + (size_t)(m0+row)*K + k0 + cc*8, &Al[buf][lbase]);
      gl_lds16(Bbf + (size_t)(n0+row)*K + k0 + cc*8, &Bl[buf][lbase]);
    }
  };

  f32x4 zero = {0.f, 0.f, 0.f, 0.f};
  f32x4 acc[4][4];
  for (int i=0;i<4;i++) for (int j=0;j<4;j++) acc[i][j] = zero;

  stageg(0, 0);
  asm volatile("s_waitcnt vmcnt(0)" ::: "memory");
  __builtin_amdgcn_s_barrier();

  for (int t = 0; t < nt; ++t) {
    int cur = t & 1;
    if (t + 1 < nt) stageg(t + 1, cur ^ 1);
    int kof = (lane >> 4) * 8;
    bf16x8 af[4], bfr[4];
    for (int i=0;i<4;i++) af[i]  = *(const bf16x8*)(&Al[cur][(wrow + i*16 + (lane&15))*BKQ + kof]);
    for (int j=0;j<4;j++) bfr[j] = *(const bf16x8*)(&Bl[cur][(wcol + j*16 + (lane&15))*BKQ + kof]);
    for (int i=0;i<4;i++)
      for (int j=0;j<4;j++)
        acc[i][j] = __builtin_amdgcn_mfma_f32_16x16x32_bf16(af[i], bfr[j], acc[i][j], 0, 0, 0);
    asm volatile("s_waitcnt vmcnt(0)" ::: "memory");
    __builtin_amdgcn_s_barrier();
  }
  for (int i=0;i<4;i++)
    for (int j=0;j<4;j++)
      for (int r=0;r<4;r++) {
        int gm = m0 + wrow + i*16 + (lane>>4)*4 + r;
        int gn = n0 + wcol + j*16 + (lane&15);
        float v = acc[i][j][r] + bias[gn];
        int b = gm >> 11, s = gm & (S_-1);
        int sect = gn >> 10, hn = gn & (D_-1);
        int hh = hn >> 6, d = hn & 63;
        size_t idx = (((size_t)(b*H_ + hh))*S_ + s)*DH_ + d;
        if (sect == 0) v *= QSCALE;
        ushort_t val = f2bf(v);
        if (sect == 0) qb[idx] = val;
        else if (sect == 1) kb[idx] = val;
        else vb[idx] = val;
      }
}

// ---------------- V transpose: [BH][S][DH] -> [BH][DH][S] ----------------
__global__ __launch_bounds__(256) void transpose_v(
    const ushort_t* __restrict__ vb, ushort_t* __restrict__ vtb) {
  __shared__ ushort_t T[64*72];
  int bh = blockIdx.y;
  int s0 = blockIdx.x * 64;
  int tid = threadIdx.x;
  const ushort_t* src = vb + (size_t)bh * S_ * DH_;
  ushort_t* dst = vtb + (size_t)bh * DH_ * S_;
  for (int it = 0; it < 2; ++it) {
    int c = it*256 + tid;
    int row = c >> 3, cc = c & 7;
    *(uint4*)&T[row*72 + cc*8] = *(const uint4*)(src + (size_t)(s0+row)*DH_ + cc*8);
  }
  __syncthreads();
  for (int it = 0; it < 2; ++it) {
    int c = it*256 + tid;
    int d = c >> 3, sc = c & 7;
    u16x8 o;
    #pragma unroll
    for (int e = 0; e < 8; ++e) o[e] = T[(sc*8+e)*72 + d];
    *(u16x8*)(dst + (size_t)d*S_ + s0 + sc*8) = o;
  }
}

// ---------------- flash attention v9 (best measured) ----------------
// 1024 blocks x 4 waves; 64-row q-blocks, 16 rows/wave; 2-buffer KV (32 KB);
// boustrophedon qblk map (equal per-CU totals); XCD-grouped bh; in-lane K=16 PV.
#define KVB 64
#define DTHR 8.0f
__global__ __launch_bounds__(256) void attn_fwd(
    const ushort_t* __restrict__ qb, const ushort_t* __restrict__ kb,
    const ushort_t* __restrict__ vtb, ushort_t* __restrict__ attnb,
    const int* __restrict__ causal) {
  int wg = blockIdx.x;                  // 0..1023
  int xcd = wg & 7;
  int j = wg >> 3;                      // 0..127 per-XCD dispatch sequence
  int v = j >> 5;                       // visit 0..3
  int u = j & 31;                       // CU slot within XCD
  int a = u >> 2;                       // qblk subgroup 0..7
  int qi = v*8 + ((v & 1) ? (7 - a) : a);   // boustrophedon: per-CU sums equal
  int qblk = 31 - qi;
  int bh = (u & 3) * 8 + xcd;           // 4 bh per XCD -> KV L2-resident
  int b = bh >> 4, h = bh & 15;
  int tid = threadIdx.x, w = tid >> 6, lane = tid & 63;
  int g = lane >> 4, q16 = lane & 15;
  const ushort_t* qh  = qb  + (size_t)bh * S_ * DH_;
  const ushort_t* kh  = kb  + (size_t)bh * S_ * DH_;
  const ushort_t* vth = vtb + (size_t)bh * DH_ * S_;
  __shared__ __align__(16) ushort_t Kl[2][KVB*64];
  __shared__ __align__(16) ushort_t Vtl[2][64*KVB];
  bool use_causal = (causal[0] != 0);

  int nkv = use_causal ? (qblk + 1) : (S_/KVB);
  int qw = qblk*64 + w*16;

  bf16x8 qc0 = *(const bf16x8*)(qh + (size_t)(qw + q16)*DH_ +  0 + g*8);
  bf16x8 qc1 = *(const bf16x8*)(qh + (size_t)(qw + q16)*DH_ + 32 + g*8);

  int c0 = tid, c1 = tid + 256;
  int r0 = c0 >> 3, sw0 = ((c0 & 7) ^ (r0 & 7)) * 8;
  int r1 = c1 >> 3, sw1 = ((c1 & 7) ^ (r1 & 7)) * 8;
  const ushort_t* kp0 = kh + r0*DH_ + sw0;
  const ushort_t* kp1 = kh + r1*DH_ + sw1;
  const ushort_t* vp0 = vth + (size_t)r0*S_ + sw0;
  const ushort_t* vp1 = vth + (size_t)r1*S_ + sw1;

  auto stage = [&](int t, int buf) {
    size_t kadv = (size_t)(t*KVB) * DH_;
    int vadv = t*KVB;
    gl_lds16(kp0 + kadv, &Kl[buf][c0*8]);
    gl_lds16(kp1 + kadv, &Kl[buf][c1*8]);
    gl_lds16(vp0 + vadv, &Vtl[buf][c0*8]);
    gl_lds16(vp1 + vadv, &Vtl[buf][c1*8]);
  };

  f32x4 zero = {0.f,0.f,0.f,0.f};
  f32x4 o[4];
  #pragma unroll
  for (int dt=0;dt<4;dt++) o[dt] = zero;
  float mrun = -1e30f, lrun = 0.f;

  stage(0, 0);
  asm volatile("s_waitcnt vmcnt(0)" ::: "memory");
  __builtin_amdgcn_s_barrier();

  for (int it = 0; it < nkv; ++it) {
    int cur = it & 1;
    int kvbase = it * KVB;
    if (it + 1 < nkv) stage(it + 1, cur ^ 1);   // lands during compute below

    f32x4 sacc[4];
    #pragma unroll
    for (int j2=0;j2<4;j2++) sacc[j2] = zero;
    #pragma unroll
    for (int kk=0;kk<2;kk++) {
      bf16x8 qf = kk ? qc1 : qc0;
      #pragma unroll
      for (int j2=0;j2<4;j2++) {
        int row = j2*16 + q16;
        int slot = (kk*4 + g) ^ (row & 7);
        bf16x8 kf = *(const bf16x8*)(&Kl[cur][row*64 + slot*8]);
        sacc[j2] = __builtin_amdgcn_mfma_f32_16x16x32_bf16(kf, qf, sacc[j2], 0, 0, 0);
      }
    }
    if (use_causal && kvbase + KVB - 1 > qw) {
      int qd = qw + q16 - kvbase;
      #pragma unroll
      for (int j2=0;j2<4;j2++)
        #pragma unroll
        for (int r=0;r<4;r++)
          if (16*j2 + 4*g + r > qd) sacc[j2][r] = -1e30f;
    }
    float m0v = fmaxf(fmaxf(sacc[0][0], sacc[0][1]), fmaxf(sacc[0][2], sacc[0][3]));
    float m1v = fmaxf(fmaxf(sacc[1][0], sacc[1][1]), fmaxf(sacc[1][2], sacc[1][3]));
    float m2v = fmaxf(fmaxf(sacc[2][0], sacc[2][1]), fmaxf(sacc[2][2], sacc[2][3]));
    float m3v = fmaxf(fmaxf(sacc[3][0], sacc[3][1]), fmaxf(sacc[3][2], sacc[3][3]));
    float mx = fmaxf(fmaxf(m0v, m1v), fmaxf(m2v, m3v));
    mx = fmaxf(mx, __shfl_xor(mx, 16, 64));
    mx = fmaxf(mx, __shfl_xor(mx, 32, 64));
    if (!__all(mx - mrun <= DTHR)) {
      float mnew = fmaxf(mrun, mx);
      float alpha = fexp2(mrun - mnew);
      lrun *= alpha;
      float av0 = __shfl(alpha, 4*g + 0, 64);
      float av1 = __shfl(alpha, 4*g + 1, 64);
      float av2 = __shfl(alpha, 4*g + 2, 64);
      float av3 = __shfl(alpha, 4*g + 3, 64);
      #pragma unroll
      for (int dt=0;dt<4;dt++) {
        o[dt][0] *= av0; o[dt][1] *= av1; o[dt][2] *= av2; o[dt][3] *= av3;
      }
      mrun = mnew;
    }
    float p[4][4];
    float rs = 0.f;
    #pragma unroll
    for (int j2=0;j2<4;j2++)
      #pragma unroll
      for (int r=0;r<4;r++) {
        p[j2][r] = fexp2(sacc[j2][r] - mrun);
        rs += p[j2][r];
      }
    rs += __shfl_xor(rs, 16, 64);
    rs += __shfl_xor(rs, 32, 64);
    lrun += rs;
    #pragma unroll
    for (int s=0;s<4;s++) {
      union { unsigned u2[2]; bf16x4 v2; } pk;
      pk.u2[0] = cvt_pk_bf16(p[s][0], p[s][1]);
      pk.u2[1] = cvt_pk_bf16(p[s][2], p[s][3]);
      int E = 16*s + 4*g;
      #pragma unroll
      for (int dt=0;dt<4;dt++) {
        int row = dt*16 + q16;
        int off = row*64 + ((E >> 3) ^ (row & 7))*8 + (E & 7);
        bf16x4 vf = *(const bf16x4*)(&Vtl[cur][off]);
        o[dt] = mfma16(pk.v2, vf, o[dt]);
      }
    }
    asm volatile("s_waitcnt vmcnt(0)" ::: "memory");
    __builtin_amdgcn_s_barrier();
  }
  float li0 = 1.f / __shfl(lrun, 4*g + 0, 64);
  float li1 = 1.f / __shfl(lrun, 4*g + 1, 64);
  float li2 = 1.f / __shfl(lrun, 4*g + 2, 64);
  float li3 = 1.f / __shfl(lrun, 4*g + 3, 64);
  #pragma unroll
  for (int r=0;r<4;r++) {
    float li = (r==0)?li0:(r==1)?li1:(r==2)?li2:li3;
    int q = qw + 4*g + r;
    #pragma unroll
    for (int dt=0;dt<4;dt++) {
      int d = dt*16 + q16;
      attnb[((size_t)(b*S_ + q))*D_ + h*DH_ + d] = f2bf(o[dt][r] * li);
    }
  }
}

// ---------------- output GEMM: out = attn @ Wo^T + bo ----------------
// 128x128 tile, BKO=64 swizzled LDS reads, 512 thr / 8 waves, 2-buffer
// pipeline (stage -> compute -> vmcnt(0) -> raw barrier).
__global__ __launch_bounds__(512) void gemm_out(
    const ushort_t* __restrict__ Abf, const ushort_t* __restrict__ Bbf,
    const float* __restrict__ bias, float* __restrict__ out) {
  __shared__ __align__(16) ushort_t Al[2][128*BKO];
  __shared__ __align__(16) ushort_t Bl[2][128*BKO];
  int tid = threadIdx.x;
  int w = tid >> 6, lane = tid & 63;
  int g = lane >> 4, q16 = lane & 15;
  int wrow = (w >> 2) * 64, wcol = (w & 3) * 32;
  int m0 = blockIdx.y * 128, n0 = blockIdx.x * 128;
  const int K = D_;
  const int nt = K / BKO;

  auto stageg = [&](int t, int buf) {
    int k0 = t * BKO;
    #pragma unroll
    for (int it = 0; it < 2; ++it) {
      int c = it*512 + tid;
      int row = c >> 3, scc = ((c & 7) ^ (row & 7)) * 8;
      gl_lds16(Abf + (size_t)(m0+row)*K + k0 + scc, &Al[buf][c*8]);
      gl_lds16(Bbf + (size_t)(n0+row)*K + k0 + scc, &Bl[buf][c*8]);
    }
  };

  f32x4 zero = {0.f,0.f,0.f,0.f};
  f32x4 acc[4][2];
  for (int i=0;i<4;i++) for (int j=0;j<2;j++) acc[i][j] = zero;

  stageg(0, 0);
  asm volatile("s_waitcnt vmcnt(0)" ::: "memory");
  __builtin_amdgcn_s_barrier();

  for (int t = 0; t < nt; ++t) {
    int cur = t & 1;
    if (t + 1 < nt) stageg(t + 1, cur ^ 1);
    #pragma unroll
    for (int kk = 0; kk < 2; ++kk) {
      bf16x8 af[4], bfr[2];
      #pragma unroll
      for (int i=0;i<4;i++) {
        int row = wrow + i*16 + q16;
        int slot = ((kk*4 + g) ^ (row & 7)) * 8;
        af[i] = *(const bf16x8*)(&Al[cur][row*BKO + slot]);
      }
      #pragma unroll
      for (int j=0;j<2;j++) {
        int row = wcol + j*16 + q16;
        int slot = ((kk*4 + g) ^ (row & 7)) * 8;
        bfr[j] = *(const bf16x8*)(&Bl[cur][row*BKO + slot]);
      }
      #pragma unroll
      for (int i=0;i<4;i++)
        #pragma unroll
        for (int j=0;j<2;j++)
          acc[i][j] = __builtin_amdgcn_mfma_f32_16x16x32_bf16(af[i], bfr[j], acc[i][j], 0, 0, 0);
    }
    asm volatile("s_waitcnt vmcnt(0)" ::: "memory");
    __builtin_amdgcn_s_barrier();
  }
  #pragma unroll
  for (int i=0;i<4;i++)
    #pragma unroll
    for (int j=0;j<2;j++)
      #pragma unroll
      for (int r=0;r<4;r++) {
        int gm = m0 + wrow + i*16 + g*4 + r;
        int gn = n0 + wcol + j*16 + q16;
        out[(size_t)gm*D_ + gn] = acc[i][j][r] + bias[gn];
      }
}

extern "C" void kernel_launch(void* const* d_in, const int* in_sizes, int n_in,
                              void* d_out, int out_size, void* d_ws, size_t ws_size,
                              hipStream_t stream) {
  const float* x  = (const float*)d_in[0];
  const float* Wi = (const float*)d_in[1];
  const float* bi = (const float*)d_in[2];
  const float* Wo = (const float*)d_in[3];
  const float* bo = (const float*)d_in[4];
  const int* causal = (const int*)d_in[5];
  float* out = (float*)d_out;

  ushort_t* xb   = (ushort_t*)d_ws;                       // 4096*1024 (reused as vtb)
  ushort_t* Wib  = xb  + (size_t)MTOT*D_;                 // 3072*1024
  ushort_t* Wob  = Wib + (size_t)NQKV*D_;                 // 1024*1024
  ushort_t* qbuf = Wob + (size_t)D_*D_;                   // 32*2048*64
  ushort_t* kbuf = qbuf + (size_t)B_*H_*S_*DH_;
  ushort_t* vbuf = kbuf + (size_t)B_*H_*S_*DH_;
  ushort_t* attnb = vbuf + (size_t)B_*H_*S_*DH_;          // 4096*1024
  ushort_t* vtb  = xb;  // xb dead after gemm_qkv; reuse for transposed V

  int ntot = CVN1 + CVN2 + CVN3;
  cvt_all<<<(ntot+255)/256, 256, 0, stream>>>(x, Wi, Wo, xb, Wib, Wob);

  gemm_qkv<<<dim3(NQKV/128, MTOT/128), 256, 0, stream>>>(xb, Wib, bi, qbuf, kbuf, vbuf);
  transpose_v<<<dim3(S_/64, B_*H_), 256, 0, stream>>>(vbuf, vtb);
  attn_fwd<<<1024, 256, 0, stream>>>(qbuf, kbuf, vtb, attnb, causal);
  gemm_out<<<dim3(D_/128, MTOT/128), 512, 0, stream>>>(attnb, Wob, bo, out);
}

// Round 16
// 114.367 us; speedup vs baseline: 1.1461x; 1.0438x over previous
//
#include <hip/hip_runtime.h>
#include <hip/hip_bf16.h>
#include <stdint.h>

#define B_    2
#define S_    2048
#define D_    1024
#define H_    16
#define DH_   64
#define MTOT  (B_*S_)     // 4096
#define NQKV  (3*D_)      // 3072

typedef __attribute__((ext_vector_type(8))) short  bf16x8;
typedef __attribute__((ext_vector_type(4))) short  bf16x4;
typedef __attribute__((ext_vector_type(4))) float  f32x4;
typedef __attribute__((ext_vector_type(8))) unsigned short u16x8;
typedef unsigned short ushort_t;

__device__ __forceinline__ ushort_t f2bf(float f) {
  union { float f; unsigned int i; } v; v.f = f;
  unsigned int r = v.i + 0x7FFF + ((v.i >> 16) & 1);
  return (ushort_t)(r >> 16);
}

__device__ __forceinline__ unsigned cvt_pk_bf16(float lo, float hi) {
  unsigned r;
  asm("v_cvt_pk_bf16_f32 %0, %1, %2" : "=v"(r) : "v"(lo), "v"(hi));
  return r;
}

__device__ __forceinline__ float fexp2(float x) {
  float r;
  asm("v_exp_f32 %0, %1" : "=v"(r) : "v"(x));
  return r;
}

// K=16 bf16 MFMA: builtin name differs across ROCm versions; chain with asm fallback.
#if __has_builtin(__builtin_amdgcn_mfma_f32_16x16x16_bf16)
__device__ __forceinline__ f32x4 mfma16(bf16x4 a, bf16x4 b, f32x4 c) {
  return __builtin_amdgcn_mfma_f32_16x16x16_bf16(a, b, c, 0, 0, 0);
}
#elif __has_builtin(__builtin_amdgcn_mfma_f32_16x16x16bf16_1k)
__device__ __forceinline__ f32x4 mfma16(bf16x4 a, bf16x4 b, f32x4 c) {
  return __builtin_amdgcn_mfma_f32_16x16x16bf16_1k(a, b, c, 0, 0, 0);
}
#else
__device__ __forceinline__ f32x4 mfma16(bf16x4 a, bf16x4 b, f32x4 c) {
  asm volatile("v_mfma_f32_16x16x16_bf16 %0, %1, %2, %0"
               : "+v"(c) : "v"(a), "v"(b));
  return c;
}
#endif

__device__ __forceinline__ void gl_lds16(const ushort_t* g, ushort_t* l) {
  __builtin_amdgcn_global_load_lds(
      (const __attribute__((address_space(1))) unsigned int*)g,
      (__attribute__((address_space(3))) unsigned int*)l, 16, 0, 0);
}

// ---------------- fused fp32 -> bf16 conversion (x, Wi, Wo) ----------------
#define CVN1 (MTOT*D_/8)
#define CVN2 (NQKV*D_/8)
#define CVN3 (D_*D_/8)
__global__ __launch_bounds__(256) void cvt_all(
    const float* __restrict__ x, const float* __restrict__ Wi, const float* __restrict__ Wo,
    ushort_t* __restrict__ xb, ushort_t* __restrict__ Wib, ushort_t* __restrict__ Wob) {
  int i = blockIdx.x * blockDim.x + threadIdx.x;
  const float* src; ushort_t* dst; int k;
  if (i < CVN1)            { src = x;  dst = xb;  k = i; }
  else if (i < CVN1+CVN2)  { src = Wi; dst = Wib; k = i - CVN1; }
  else                     { src = Wo; dst = Wob; k = i - CVN1 - CVN2; }
  const float4* s4 = (const float4*)src;
  float4 a = s4[2*k], b = s4[2*k+1];
  u16x8 o;
  o[0]=f2bf(a.x); o[1]=f2bf(a.y); o[2]=f2bf(a.z); o[3]=f2bf(a.w);
  o[4]=f2bf(b.x); o[5]=f2bf(b.y); o[6]=f2bf(b.z); o[7]=f2bf(b.w);
  ((u16x8*)dst)[k] = o;
}

// ---------------- QKV GEMM: qkv = x @ Wi^T + bi ----------------
// Ported to the proven gemm_out structure: 512 thr / 8 waves (2Mx4N, 64x32
// per wave), BK=64 with XOR-swizzled ds_reads, 2-buffer raw-barrier pipeline;
// chunked XCD swizzle over 768 blocks; q/k/v scatter epilogue.
#define BKO 64
// scale folded into q: 1/sqrt(64) * log2(e)  (exp2-domain softmax)
#define QSCALE 0.18033688011112042f
__global__ __launch_bounds__(512) void gemm_qkv(
    const ushort_t* __restrict__ Abf, const ushort_t* __restrict__ Bbf,
    const float* __restrict__ bias,
    ushort_t* __restrict__ qb, ushort_t* __restrict__ kb, ushort_t* __restrict__ vb) {
  __shared__ __align__(16) ushort_t Al[2][128*BKO];
  __shared__ __align__(16) ushort_t Bl[2][128*BKO];
  int tid = threadIdx.x;
  int w = tid >> 6, lane = tid & 63;
  int g = lane >> 4, q16 = lane & 15;
  int wrow = (w >> 2) * 64, wcol = (w & 3) * 32;
  // chunked XCD swizzle: bid 0..767, 96 consecutive per XCD
  int bid = blockIdx.y * 24 + blockIdx.x;
  int swz = (bid & 7) * 96 + (bid >> 3);
  int m0 = (swz / 24) * 128, n0 = (swz % 24) * 128;
  const int K = D_;
  const int nt = K / BKO;

  auto stageg = [&](int t, int buf) {
    int k0 = t * BKO;
    #pragma unroll
    for (int it = 0; it < 2; ++it) {
      int c = it*512 + tid;
      int row = c >> 3, scc = ((c & 7) ^ (row & 7)) * 8;
      gl_lds16(Abf + (size_t)(m0+row)*K + k0 + scc, &Al[buf][c*8]);
      gl_lds16(Bbf + (size_t)(n0+row)*K + k0 + scc, &Bl[buf][c*8]);
    }
  };

  f32x4 zero = {0.f,0.f,0.f,0.f};
  f32x4 acc[4][2];
  for (int i=0;i<4;i++) for (int j=0;j<2;j++) acc[i][j] = zero;

  stageg(0, 0);
  asm volatile("s_waitcnt vmcnt(0)" ::: "memory");
  __builtin_amdgcn_s_barrier();

  for (int t = 0; t < nt; ++t) {
    int cur = t & 1;
    if (t + 1 < nt) stageg(t + 1, cur ^ 1);
    #pragma unroll
    for (int kk = 0; kk < 2; ++kk) {
      bf16x8 af[4], bfr[2];
      #pragma unroll
      for (int i=0;i<4;i++) {
        int row = wrow + i*16 + q16;
        int slot = ((kk*4 + g) ^ (row & 7)) * 8;
        af[i] = *(const bf16x8*)(&Al[cur][row*BKO + slot]);
      }
      #pragma unroll
      for (int j=0;j<2;j++) {
        int row = wcol + j*16 + q16;
        int slot = ((kk*4 + g) ^ (row & 7)) * 8;
        bfr[j] = *(const bf16x8*)(&Bl[cur][row*BKO + slot]);
      }
      #pragma unroll
      for (int i=0;i<4;i++)
        #pragma unroll
        for (int j=0;j<2;j++)
          acc[i][j] = __builtin_amdgcn_mfma_f32_16x16x32_bf16(af[i], bfr[j], acc[i][j], 0, 0, 0);
    }
    asm volatile("s_waitcnt vmcnt(0)" ::: "memory");
    __builtin_amdgcn_s_barrier();
  }
  // epilogue: scatter into q/k/v head layouts [B][H][S][DH]
  #pragma unroll
  for (int i=0;i<4;i++)
    #pragma unroll
    for (int j=0;j<2;j++)
      #pragma unroll
      for (int r=0;r<4;r++) {
        int gm = m0 + wrow + i*16 + g*4 + r;
        int gn = n0 + wcol + j*16 + q16;
        float v = acc[i][j][r] + bias[gn];
        int b = gm >> 11, s = gm & (S_-1);
        int sect = gn >> 10, hn = gn & (D_-1);
        int hh = hn >> 6, d = hn & 63;
        size_t idx = (((size_t)(b*H_ + hh))*S_ + s)*DH_ + d;
        if (sect == 0) v *= QSCALE;
        ushort_t val = f2bf(v);
        if (sect == 0) qb[idx] = val;
        else if (sect == 1) kb[idx] = val;
        else vb[idx] = val;
      }
}

// ---------------- V transpose: [BH][S][DH] -> [BH][DH][S] ----------------
__global__ __launch_bounds__(256) void transpose_v(
    const ushort_t* __restrict__ vb, ushort_t* __restrict__ vtb) {
  __shared__ ushort_t T[64*72];
  int bh = blockIdx.y;
  int s0 = blockIdx.x * 64;
  int tid = threadIdx.x;
  const ushort_t* src = vb + (size_t)bh * S_ * DH_;
  ushort_t* dst = vtb + (size_t)bh * DH_ * S_;
  for (int it = 0; it < 2; ++it) {
    int c = it*256 + tid;
    int row = c >> 3, cc = c & 7;
    *(uint4*)&T[row*72 + cc*8] = *(const uint4*)(src + (size_t)(s0+row)*DH_ + cc*8);
  }
  __syncthreads();
  for (int it = 0; it < 2; ++it) {
    int c = it*256 + tid;
    int d = c >> 3, sc = c & 7;
    u16x8 o;
    #pragma unroll
    for (int e = 0; e < 8; ++e) o[e] = T[(sc*8+e)*72 + d];
    *(u16x8*)(dst + (size_t)d*S_ + s0 + sc*8) = o;
  }
}

// ---------------- flash attention v9 (best measured) ----------------
// 1024 blocks x 4 waves; 64-row q-blocks, 16 rows/wave; 2-buffer KV (32 KB);
// boustrophedon qblk map (equal per-CU totals); XCD-grouped bh; in-lane K=16 PV.
#define KVB 64
#define DTHR 8.0f
__global__ __launch_bounds__(256) void attn_fwd(
    const ushort_t* __restrict__ qb, const ushort_t* __restrict__ kb,
    const ushort_t* __restrict__ vtb, ushort_t* __restrict__ attnb,
    const int* __restrict__ causal) {
  int wg = blockIdx.x;                  // 0..1023
  int xcd = wg & 7;
  int j = wg >> 3;                      // 0..127 per-XCD dispatch sequence
  int v = j >> 5;                       // visit 0..3
  int u = j & 31;                       // CU slot within XCD
  int a = u >> 2;                       // qblk subgroup 0..7
  int qi = v*8 + ((v & 1) ? (7 - a) : a);   // boustrophedon: per-CU sums equal
  int qblk = 31 - qi;
  int bh = (u & 3) * 8 + xcd;           // 4 bh per XCD -> KV L2-resident
  int b = bh >> 4, h = bh & 15;
  int tid = threadIdx.x, w = tid >> 6, lane = tid & 63;
  int g = lane >> 4, q16 = lane & 15;
  const ushort_t* qh  = qb  + (size_t)bh * S_ * DH_;
  const ushort_t* kh  = kb  + (size_t)bh * S_ * DH_;
  const ushort_t* vth = vtb + (size_t)bh * DH_ * S_;
  __shared__ __align__(16) ushort_t Kl[2][KVB*64];
  __shared__ __align__(16) ushort_t Vtl[2][64*KVB];
  bool use_causal = (causal[0] != 0);

  int nkv = use_causal ? (qblk + 1) : (S_/KVB);
  int qw = qblk*64 + w*16;

  bf16x8 qc0 = *(const bf16x8*)(qh + (size_t)(qw + q16)*DH_ +  0 + g*8);
  bf16x8 qc1 = *(const bf16x8*)(qh + (size_t)(qw + q16)*DH_ + 32 + g*8);

  int c0 = tid, c1 = tid + 256;
  int r0 = c0 >> 3, sw0 = ((c0 & 7) ^ (r0 & 7)) * 8;
  int r1 = c1 >> 3, sw1 = ((c1 & 7) ^ (r1 & 7)) * 8;
  const ushort_t* kp0 = kh + r0*DH_ + sw0;
  const ushort_t* kp1 = kh + r1*DH_ + sw1;
  const ushort_t* vp0 = vth + (size_t)r0*S_ + sw0;
  const ushort_t* vp1 = vth + (size_t)r1*S_ + sw1;

  auto stage = [&](int t, int buf) {
    size_t kadv = (size_t)(t*KVB) * DH_;
    int vadv = t*KVB;
    gl_lds16(kp0 + kadv, &Kl[buf][c0*8]);
    gl_lds16(kp1 + kadv, &Kl[buf][c1*8]);
    gl_lds16(vp0 + vadv, &Vtl[buf][c0*8]);
    gl_lds16(vp1 + vadv, &Vtl[buf][c1*8]);
  };

  f32x4 zero = {0.f,0.f,0.f,0.f};
  f32x4 o[4];
  #pragma unroll
  for (int dt=0;dt<4;dt++) o[dt] = zero;
  float mrun = -1e30f, lrun = 0.f;

  stage(0, 0);
  asm volatile("s_waitcnt vmcnt(0)" ::: "memory");
  __builtin_amdgcn_s_barrier();

  for (int it = 0; it < nkv; ++it) {
    int cur = it & 1;
    int kvbase = it * KVB;
    if (it + 1 < nkv) stage(it + 1, cur ^ 1);   // lands during compute below

    f32x4 sacc[4];
    #pragma unroll
    for (int j2=0;j2<4;j2++) sacc[j2] = zero;
    #pragma unroll
    for (int kk=0;kk<2;kk++) {
      bf16x8 qf = kk ? qc1 : qc0;
      #pragma unroll
      for (int j2=0;j2<4;j2++) {
        int row = j2*16 + q16;
        int slot = (kk*4 + g) ^ (row & 7);
        bf16x8 kf = *(const bf16x8*)(&Kl[cur][row*64 + slot*8]);
        sacc[j2] = __builtin_amdgcn_mfma_f32_16x16x32_bf16(kf, qf, sacc[j2], 0, 0, 0);
      }
    }
    if (use_causal && kvbase + KVB - 1 > qw) {
      int qd = qw + q16 - kvbase;
      #pragma unroll
      for (int j2=0;j2<4;j2++)
        #pragma unroll
        for (int r=0;r<4;r++)
          if (16*j2 + 4*g + r > qd) sacc[j2][r] = -1e30f;
    }
    float m0v = fmaxf(fmaxf(sacc[0][0], sacc[0][1]), fmaxf(sacc[0][2], sacc[0][3]));
    float m1v = fmaxf(fmaxf(sacc[1][0], sacc[1][1]), fmaxf(sacc[1][2], sacc[1][3]));
    float m2v = fmaxf(fmaxf(sacc[2][0], sacc[2][1]), fmaxf(sacc[2][2], sacc[2][3]));
    float m3v = fmaxf(fmaxf(sacc[3][0], sacc[3][1]), fmaxf(sacc[3][2], sacc[3][3]));
    float mx = fmaxf(fmaxf(m0v, m1v), fmaxf(m2v, m3v));
    mx = fmaxf(mx, __shfl_xor(mx, 16, 64));
    mx = fmaxf(mx, __shfl_xor(mx, 32, 64));
    if (!__all(mx - mrun <= DTHR)) {
      float mnew = fmaxf(mrun, mx);
      float alpha = fexp2(mrun - mnew);
      lrun *= alpha;
      float av0 = __shfl(alpha, 4*g + 0, 64);
      float av1 = __shfl(alpha, 4*g + 1, 64);
      float av2 = __shfl(alpha, 4*g + 2, 64);
      float av3 = __shfl(alpha, 4*g + 3, 64);
      #pragma unroll
      for (int dt=0;dt<4;dt++) {
        o[dt][0] *= av0; o[dt][1] *= av1; o[dt][2] *= av2; o[dt][3] *= av3;
      }
      mrun = mnew;
    }
    float p[4][4];
    float rs = 0.f;
    #pragma unroll
    for (int j2=0;j2<4;j2++)
      #pragma unroll
      for (int r=0;r<4;r++) {
        p[j2][r] = fexp2(sacc[j2][r] - mrun);
        rs += p[j2][r];
      }
    rs += __shfl_xor(rs, 16, 64);
    rs += __shfl_xor(rs, 32, 64);
    lrun += rs;
    #pragma unroll
    for (int s=0;s<4;s++) {
      union { unsigned u2[2]; bf16x4 v2; } pk;
      pk.u2[0] = cvt_pk_bf16(p[s][0], p[s][1]);
      pk.u2[1] = cvt_pk_bf16(p[s][2], p[s][3]);
      int E = 16*s + 4*g;
      #pragma unroll
      for (int dt=0;dt<4;dt++) {
        int row = dt*16 + q16;
        int off = row*64 + ((E >> 3) ^ (row & 7))*8 + (E & 7);
        bf16x4 vf = *(const bf16x4*)(&Vtl[cur][off]);
        o[dt] = mfma16(pk.v2, vf, o[dt]);
      }
    }
    asm volatile("s_waitcnt vmcnt(0)" ::: "memory");
    __builtin_amdgcn_s_barrier();
  }
  float li0 = 1.f / __shfl(lrun, 4*g + 0, 64);
  float li1 = 1.f / __shfl(lrun, 4*g + 1, 64);
  float li2 = 1.f / __shfl(lrun, 4*g + 2, 64);
  float li3 = 1.f / __shfl(lrun, 4*g + 3, 64);
  #pragma unroll
  for (int r=0;r<4;r++) {
    float li = (r==0)?li0:(r==1)?li1:(r==2)?li2:li3;
    int q = qw + 4*g + r;
    #pragma unroll
    for (int dt=0;dt<4;dt++) {
      int d = dt*16 + q16;
      attnb[((size_t)(b*S_ + q))*D_ + h*DH_ + d] = f2bf(o[dt][r] * li);
    }
  }
}

// ---------------- output GEMM: out = attn @ Wo^T + bo ----------------
// 128x128 tile, BKO=64 swizzled LDS reads, 512 thr / 8 waves, 2-buffer
// pipeline (stage -> compute -> vmcnt(0) -> raw barrier).
__global__ __launch_bounds__(512) void gemm_out(
    const ushort_t* __restrict__ Abf, const ushort_t* __restrict__ Bbf,
    const float* __restrict__ bias, float* __restrict__ out) {
  __shared__ __align__(16) ushort_t Al[2][128*BKO];
  __shared__ __align__(16) ushort_t Bl[2][128*BKO];
  int tid = threadIdx.x;
  int w = tid >> 6, lane = tid & 63;
  int g = lane >> 4, q16 = lane & 15;
  int wrow = (w >> 2) * 64, wcol = (w & 3) * 32;
  int m0 = blockIdx.y * 128, n0 = blockIdx.x * 128;
  const int K = D_;
  const int nt = K / BKO;

  auto stageg = [&](int t, int buf) {
    int k0 = t * BKO;
    #pragma unroll
    for (int it = 0; it < 2; ++it) {
      int c = it*512 + tid;
      int row = c >> 3, scc = ((c & 7) ^ (row & 7)) * 8;
      gl_lds16(Abf + (size_t)(m0+row)*K + k0 + scc, &Al[buf][c*8]);
      gl_lds16(Bbf + (size_t)(n0+row)*K + k0 + scc, &Bl[buf][c*8]);
    }
  };

  f32x4 zero = {0.f,0.f,0.f,0.f};
  f32x4 acc[4][2];
  for (int i=0;i<4;i++) for (int j=0;j<2;j++) acc[i][j] = zero;

  stageg(0, 0);
  asm volatile("s_waitcnt vmcnt(0)" ::: "memory");
  __builtin_amdgcn_s_barrier();

  for (int t = 0; t < nt; ++t) {
    int cur = t & 1;
    if (t + 1 < nt) stageg(t + 1, cur ^ 1);
    #pragma unroll
    for (int kk = 0; kk < 2; ++kk) {
      bf16x8 af[4], bfr[2];
      #pragma unroll
      for (int i=0;i<4;i++) {
        int row = wrow + i*16 + q16;
        int slot = ((kk*4 + g) ^ (row & 7)) * 8;
        af[i] = *(const bf16x8*)(&Al[cur][row*BKO + slot]);
      }
      #pragma unroll
      for (int j=0;j<2;j++) {
        int row = wcol + j*16 + q16;
        int slot = ((kk*4 + g) ^ (row & 7)) * 8;
        bfr[j] = *(const bf16x8*)(&Bl[cur][row*BKO + slot]);
      }
      #pragma unroll
      for (int i=0;i<4;i++)
        #pragma unroll
        for (int j=0;j<2;j++)
          acc[i][j] = __builtin_amdgcn_mfma_f32_16x16x32_bf16(af[i], bfr[j], acc[i][j], 0, 0, 0);
    }
    asm volatile("s_waitcnt vmcnt(0)" ::: "memory");
    __builtin_amdgcn_s_barrier();
  }
  #pragma unroll
  for (int i=0;i<4;i++)
    #pragma unroll
    for (int j=0;j<2;j++)
      #pragma unroll
      for (int r=0;r<4;r++) {
        int gm = m0 + wrow + i*16 + g*4 + r;
        int gn = n0 + wcol + j*16 + q16;
        out[(size_t)gm*D_ + gn] = acc[i][j][r] + bias[gn];
      }
}

extern "C" void kernel_launch(void* const* d_in, const int* in_sizes, int n_in,
                              void* d_out, int out_size, void* d_ws, size_t ws_size,
                              hipStream_t stream) {
  const float* x  = (const float*)d_in[0];
  const float* Wi = (const float*)d_in[1];
  const float* bi = (const float*)d_in[2];
  const float* Wo = (const float*)d_in[3];
  const float* bo = (const float*)d_in[4];
  const int* causal = (const int*)d_in[5];
  float* out = (float*)d_out;

  ushort_t* xb   = (ushort_t*)d_ws;                       // 4096*1024 (reused as vtb)
  ushort_t* Wib  = xb  + (size_t)MTOT*D_;                 // 3072*1024
  ushort_t* Wob  = Wib + (size_t)NQKV*D_;                 // 1024*1024
  ushort_t* qbuf = Wob + (size_t)D_*D_;                   // 32*2048*64
  ushort_t* kbuf = qbuf + (size_t)B_*H_*S_*DH_;
  ushort_t* vbuf = kbuf + (size_t)B_*H_*S_*DH_;
  ushort_t* attnb = vbuf + (size_t)B_*H_*S_*DH_;          // 4096*1024
  ushort_t* vtb  = xb;  // xb dead after gemm_qkv; reuse for transposed V

  int ntot = CVN1 + CVN2 + CVN3;
  cvt_all<<<(ntot+255)/256, 256, 0, stream>>>(x, Wi, Wo, xb, Wib, Wob);

  gemm_qkv<<<dim3(NQKV/128, MTOT/128), 512, 0, stream>>>(xb, Wib, bi, qbuf, kbuf, vbuf);
  transpose_v<<<dim3(S_/64, B_*H_), 256, 0, stream>>>(vbuf, vtb);
  attn_fwd<<<1024, 256, 0, stream>>>(qbuf, kbuf, vtb, attnb, causal);
  gemm_out<<<dim3(D_/128, MTOT/128), 512, 0, stream>>>(attnb, Wob, bo, out);
}

// Round 18
// 113.870 us; speedup vs baseline: 1.1511x; 1.0044x over previous
//
#include <hip/hip_runtime.h>
#include <hip/hip_bf16.h>
#include <stdint.h>

#define B_    2
#define S_    2048
#define D_    1024
#define H_    16
#define DH_   64
#define MTOT  (B_*S_)     // 4096
#define NQKV  (3*D_)      // 3072

typedef __attribute__((ext_vector_type(8))) short  bf16x8;
typedef __attribute__((ext_vector_type(4))) short  bf16x4;
typedef __attribute__((ext_vector_type(4))) float  f32x4;
typedef __attribute__((ext_vector_type(8))) unsigned short u16x8;
typedef unsigned short ushort_t;

__device__ __forceinline__ ushort_t f2bf(float f) {
  union { float f; unsigned int i; } v; v.f = f;
  unsigned int r = v.i + 0x7FFF + ((v.i >> 16) & 1);
  return (ushort_t)(r >> 16);
}

__device__ __forceinline__ unsigned cvt_pk_bf16(float lo, float hi) {
  unsigned r;
  asm("v_cvt_pk_bf16_f32 %0, %1, %2" : "=v"(r) : "v"(lo), "v"(hi));
  return r;
}

__device__ __forceinline__ float fexp2(float x) {
  float r;
  asm("v_exp_f32 %0, %1" : "=v"(r) : "v"(x));
  return r;
}

// K=16 bf16 MFMA: builtin name differs across ROCm versions; chain with asm fallback.
#if __has_builtin(__builtin_amdgcn_mfma_f32_16x16x16_bf16)
__device__ __forceinline__ f32x4 mfma16(bf16x4 a, bf16x4 b, f32x4 c) {
  return __builtin_amdgcn_mfma_f32_16x16x16_bf16(a, b, c, 0, 0, 0);
}
#elif __has_builtin(__builtin_amdgcn_mfma_f32_16x16x16bf16_1k)
__device__ __forceinline__ f32x4 mfma16(bf16x4 a, bf16x4 b, f32x4 c) {
  return __builtin_amdgcn_mfma_f32_16x16x16bf16_1k(a, b, c, 0, 0, 0);
}
#else
__device__ __forceinline__ f32x4 mfma16(bf16x4 a, bf16x4 b, f32x4 c) {
  asm volatile("v_mfma_f32_16x16x16_bf16 %0, %1, %2, %0"
               : "+v"(c) : "v"(a), "v"(b));
  return c;
}
#endif

__device__ __forceinline__ void gl_lds16(const ushort_t* g, ushort_t* l) {
  __builtin_amdgcn_global_load_lds(
      (const __attribute__((address_space(1))) unsigned int*)g,
      (__attribute__((address_space(3))) unsigned int*)l, 16, 0, 0);
}

// ---------------- fused fp32 -> bf16 conversion (x, Wi, Wo) ----------------
#define CVN1 (MTOT*D_/8)
#define CVN2 (NQKV*D_/8)
#define CVN3 (D_*D_/8)
__global__ __launch_bounds__(256) void cvt_all(
    const float* __restrict__ x, const float* __restrict__ Wi, const float* __restrict__ Wo,
    ushort_t* __restrict__ xb, ushort_t* __restrict__ Wib, ushort_t* __restrict__ Wob) {
  int i = blockIdx.x * blockDim.x + threadIdx.x;
  const float* src; ushort_t* dst; int k;
  if (i < CVN1)            { src = x;  dst = xb;  k = i; }
  else if (i < CVN1+CVN2)  { src = Wi; dst = Wib; k = i - CVN1; }
  else                     { src = Wo; dst = Wob; k = i - CVN1 - CVN2; }
  const float4* s4 = (const float4*)src;
  float4 a = s4[2*k], b = s4[2*k+1];
  u16x8 o;
  o[0]=f2bf(a.x); o[1]=f2bf(a.y); o[2]=f2bf(a.z); o[3]=f2bf(a.w);
  o[4]=f2bf(b.x); o[5]=f2bf(b.y); o[6]=f2bf(b.z); o[7]=f2bf(b.w);
  ((u16x8*)dst)[k] = o;
}

// ---------------- QKV GEMM: qkv = x @ Wi^T + bi ----------------
// gemm_out structure: 512 thr / 8 waves (2Mx4N, 64x32/wave), BK=64 swizzled,
// 2-buffer raw-barrier pipeline; chunked XCD swizzle; q/k/v scatter epilogue.
#define BKO 64
// scale folded into q: 1/sqrt(64) * log2(e)  (exp2-domain softmax)
#define QSCALE 0.18033688011112042f
__global__ __launch_bounds__(512) void gemm_qkv(
    const ushort_t* __restrict__ Abf, const ushort_t* __restrict__ Bbf,
    const float* __restrict__ bias,
    ushort_t* __restrict__ qb, ushort_t* __restrict__ kb, ushort_t* __restrict__ vb) {
  __shared__ __align__(16) ushort_t Al[2][128*BKO];
  __shared__ __align__(16) ushort_t Bl[2][128*BKO];
  int tid = threadIdx.x;
  int w = tid >> 6, lane = tid & 63;
  int g = lane >> 4, q16 = lane & 15;
  int wrow = (w >> 2) * 64, wcol = (w & 3) * 32;
  int bid = blockIdx.y * 24 + blockIdx.x;
  int swz = (bid & 7) * 96 + (bid >> 3);
  int m0 = (swz / 24) * 128, n0 = (swz % 24) * 128;
  const int K = D_;
  const int nt = K / BKO;

  auto stageg = [&](int t, int buf) {
    int k0 = t * BKO;
    #pragma unroll
    for (int it = 0; it < 2; ++it) {
      int c = it*512 + tid;
      int row = c >> 3, scc = ((c & 7) ^ (row & 7)) * 8;
      gl_lds16(Abf + (size_t)(m0+row)*K + k0 + scc, &Al[buf][c*8]);
      gl_lds16(Bbf + (size_t)(n0+row)*K + k0 + scc, &Bl[buf][c*8]);
    }
  };

  f32x4 zero = {0.f,0.f,0.f,0.f};
  f32x4 acc[4][2];
  for (int i=0;i<4;i++) for (int j=0;j<2;j++) acc[i][j] = zero;

  stageg(0, 0);
  asm volatile("s_waitcnt vmcnt(0)" ::: "memory");
  __builtin_amdgcn_s_barrier();

  for (int t = 0; t < nt; ++t) {
    int cur = t & 1;
    if (t + 1 < nt) stageg(t + 1, cur ^ 1);
    #pragma unroll
    for (int kk = 0; kk < 2; ++kk) {
      bf16x8 af[4], bfr[2];
      #pragma unroll
      for (int i=0;i<4;i++) {
        int row = wrow + i*16 + q16;
        int slot = ((kk*4 + g) ^ (row & 7)) * 8;
        af[i] = *(const bf16x8*)(&Al[cur][row*BKO + slot]);
      }
      #pragma unroll
      for (int j=0;j<2;j++) {
        int row = wcol + j*16 + q16;
        int slot = ((kk*4 + g) ^ (row & 7)) * 8;
        bfr[j] = *(const bf16x8*)(&Bl[cur][row*BKO + slot]);
      }
      #pragma unroll
      for (int i=0;i<4;i++)
        #pragma unroll
        for (int j=0;j<2;j++)
          acc[i][j] = __builtin_amdgcn_mfma_f32_16x16x32_bf16(af[i], bfr[j], acc[i][j], 0, 0, 0);
    }
    asm volatile("s_waitcnt vmcnt(0)" ::: "memory");
    __builtin_amdgcn_s_barrier();
  }
  #pragma unroll
  for (int i=0;i<4;i++)
    #pragma unroll
    for (int j=0;j<2;j++)
      #pragma unroll
      for (int r=0;r<4;r++) {
        int gm = m0 + wrow + i*16 + g*4 + r;
        int gn = n0 + wcol + j*16 + q16;
        float v = acc[i][j][r] + bias[gn];
        int b = gm >> 11, s = gm & (S_-1);
        int sect = gn >> 10, hn = gn & (D_-1);
        int hh = hn >> 6, d = hn & 63;
        size_t idx = (((size_t)(b*H_ + hh))*S_ + s)*DH_ + d;
        if (sect == 0) v *= QSCALE;
        ushort_t val = f2bf(v);
        if (sect == 0) qb[idx] = val;
        else if (sect == 1) kb[idx] = val;
        else vb[idx] = val;
      }
}

// ---------------- V transpose: [BH][S][DH] -> [BH][DH][S] ----------------
__global__ __launch_bounds__(256) void transpose_v(
    const ushort_t* __restrict__ vb, ushort_t* __restrict__ vtb) {
  __shared__ ushort_t T[64*72];
  int bh = blockIdx.y;
  int s0 = blockIdx.x * 64;
  int tid = threadIdx.x;
  const ushort_t* src = vb + (size_t)bh * S_ * DH_;
  ushort_t* dst = vtb + (size_t)bh * DH_ * S_;
  for (int it = 0; it < 2; ++it) {
    int c = it*256 + tid;
    int row = c >> 3, cc = c & 7;
    *(uint4*)&T[row*72 + cc*8] = *(const uint4*)(src + (size_t)(s0+row)*DH_ + cc*8);
  }
  __syncthreads();
  for (int it = 0; it < 2; ++it) {
    int c = it*256 + tid;
    int d = c >> 3, sc = c & 7;
    u16x8 o;
    #pragma unroll
    for (int e = 0; e < 8; ++e) o[e] = T[(sc*8+e)*72 + d];
    *(u16x8*)(dst + (size_t)d*S_ + s0 + sc*8) = o;
  }
}

// ---------------- flash attention v9 (best measured) ----------------
// 1024 blocks x 4 waves; 64-row q-blocks, 16 rows/wave; 2-buffer KV (32 KB);
// boustrophedon qblk map (equal per-CU totals); XCD-grouped bh; in-lane K=16 PV.
#define KVB 64
#define DTHR 8.0f
__global__ __launch_bounds__(256) void attn_fwd(
    const ushort_t* __restrict__ qb, const ushort_t* __restrict__ kb,
    const ushort_t* __restrict__ vtb, ushort_t* __restrict__ attnb,
    const int* __restrict__ causal) {
  int wg = blockIdx.x;                  // 0..1023
  int xcd = wg & 7;
  int j = wg >> 3;                      // 0..127 per-XCD dispatch sequence
  int v = j >> 5;                       // visit 0..3
  int u = j & 31;                       // CU slot within XCD
  int a = u >> 2;                       // qblk subgroup 0..7
  int qi = v*8 + ((v & 1) ? (7 - a) : a);   // boustrophedon: per-CU sums equal
  int qblk = 31 - qi;
  int bh = (u & 3) * 8 + xcd;           // 4 bh per XCD -> KV L2-resident
  int b = bh >> 4, h = bh & 15;
  int tid = threadIdx.x, w = tid >> 6, lane = tid & 63;
  int g = lane >> 4, q16 = lane & 15;
  const ushort_t* qh  = qb  + (size_t)bh * S_ * DH_;
  const ushort_t* kh  = kb  + (size_t)bh * S_ * DH_;
  const ushort_t* vth = vtb + (size_t)bh * DH_ * S_;
  __shared__ __align__(16) ushort_t Kl[2][KVB*64];
  __shared__ __align__(16) ushort_t Vtl[2][64*KVB];
  bool use_causal = (causal[0] != 0);

  int nkv = use_causal ? (qblk + 1) : (S_/KVB);
  int qw = qblk*64 + w*16;

  bf16x8 qc0 = *(const bf16x8*)(qh + (size_t)(qw + q16)*DH_ +  0 + g*8);
  bf16x8 qc1 = *(const bf16x8*)(qh + (size_t)(qw + q16)*DH_ + 32 + g*8);

  int c0 = tid, c1 = tid + 256;
  int r0 = c0 >> 3, sw0 = ((c0 & 7) ^ (r0 & 7)) * 8;
  int r1 = c1 >> 3, sw1 = ((c1 & 7) ^ (r1 & 7)) * 8;
  const ushort_t* kp0 = kh + r0*DH_ + sw0;
  const ushort_t* kp1 = kh + r1*DH_ + sw1;
  const ushort_t* vp0 = vth + (size_t)r0*S_ + sw0;
  const ushort_t* vp1 = vth + (size_t)r1*S_ + sw1;

  auto stage = [&](int t, int buf) {
    size_t kadv = (size_t)(t*KVB) * DH_;
    int vadv = t*KVB;
    gl_lds16(kp0 + kadv, &Kl[buf][c0*8]);
    gl_lds16(kp1 + kadv, &Kl[buf][c1*8]);
    gl_lds16(vp0 + vadv, &Vtl[buf][c0*8]);
    gl_lds16(vp1 + vadv, &Vtl[buf][c1*8]);
  };

  f32x4 zero = {0.f,0.f,0.f,0.f};
  f32x4 o[4];
  #pragma unroll
  for (int dt=0;dt<4;dt++) o[dt] = zero;
  float mrun = -1e30f, lrun = 0.f;

  stage(0, 0);
  asm volatile("s_waitcnt vmcnt(0)" ::: "memory");
  __builtin_amdgcn_s_barrier();

  for (int it = 0; it < nkv; ++it) {
    int cur = it & 1;
    int kvbase = it * KVB;
    if (it + 1 < nkv) stage(it + 1, cur ^ 1);   // lands during compute below

    f32x4 sacc[4];
    #pragma unroll
    for (int j2=0;j2<4;j2++) sacc[j2] = zero;
    #pragma unroll
    for (int kk=0;kk<2;kk++) {
      bf16x8 qf = kk ? qc1 : qc0;
      #pragma unroll
      for (int j2=0;j2<4;j2++) {
        int row = j2*16 + q16;
        int slot = (kk*4 + g) ^ (row & 7);
        bf16x8 kf = *(const bf16x8*)(&Kl[cur][row*64 + slot*8]);
        sacc[j2] = __builtin_amdgcn_mfma_f32_16x16x32_bf16(kf, qf, sacc[j2], 0, 0, 0);
      }
    }
    if (use_causal && kvbase + KVB - 1 > qw) {
      int qd = qw + q16 - kvbase;
      #pragma unroll
      for (int j2=0;j2<4;j2++)
        #pragma unroll
        for (int r=0;r<4;r++)
          if (16*j2 + 4*g + r > qd) sacc[j2][r] = -1e30f;
    }
    float m0v = fmaxf(fmaxf(sacc[0][0], sacc[0][1]), fmaxf(sacc[0][2], sacc[0][3]));
    float m1v = fmaxf(fmaxf(sacc[1][0], sacc[1][1]), fmaxf(sacc[1][2], sacc[1][3]));
    float m2v = fmaxf(fmaxf(sacc[2][0], sacc[2][1]), fmaxf(sacc[2][2], sacc[2][3]));
    float m3v = fmaxf(fmaxf(sacc[3][0], sacc[3][1]), fmaxf(sacc[3][2], sacc[3][3]));
    float mx = fmaxf(fmaxf(m0v, m1v), fmaxf(m2v, m3v));
    mx = fmaxf(mx, __shfl_xor(mx, 16, 64));
    mx = fmaxf(mx, __shfl_xor(mx, 32, 64));
    if (!__all(mx - mrun <= DTHR)) {
      float mnew = fmaxf(mrun, mx);
      float alpha = fexp2(mrun - mnew);
      lrun *= alpha;
      float av0 = __shfl(alpha, 4*g + 0, 64);
      float av1 = __shfl(alpha, 4*g + 1, 64);
      float av2 = __shfl(alpha, 4*g + 2, 64);
      float av3 = __shfl(alpha, 4*g + 3, 64);
      #pragma unroll
      for (int dt=0;dt<4;dt++) {
        o[dt][0] *= av0; o[dt][1] *= av1; o[dt][2] *= av2; o[dt][3] *= av3;
      }
      mrun = mnew;
    }
    float p[4][4];
    float rs = 0.f;
    #pragma unroll
    for (int j2=0;j2<4;j2++)
      #pragma unroll
      for (int r=0;r<4;r++) {
        p[j2][r] = fexp2(sacc[j2][r] - mrun);
        rs += p[j2][r];
      }
    rs += __shfl_xor(rs, 16, 64);
    rs += __shfl_xor(rs, 32, 64);
    lrun += rs;
    #pragma unroll
    for (int s=0;s<4;s++) {
      union { unsigned u2[2]; bf16x4 v2; } pk;
      pk.u2[0] = cvt_pk_bf16(p[s][0], p[s][1]);
      pk.u2[1] = cvt_pk_bf16(p[s][2], p[s][3]);
      int E = 16*s + 4*g;
      #pragma unroll
      for (int dt=0;dt<4;dt++) {
        int row = dt*16 + q16;
        int off = row*64 + ((E >> 3) ^ (row & 7))*8 + (E & 7);
        bf16x4 vf = *(const bf16x4*)(&Vtl[cur][off]);
        o[dt] = mfma16(pk.v2, vf, o[dt]);
      }
    }
    asm volatile("s_waitcnt vmcnt(0)" ::: "memory");
    __builtin_amdgcn_s_barrier();
  }
  float li0 = 1.f / __shfl(lrun, 4*g + 0, 64);
  float li1 = 1.f / __shfl(lrun, 4*g + 1, 64);
  float li2 = 1.f / __shfl(lrun, 4*g + 2, 64);
  float li3 = 1.f / __shfl(lrun, 4*g + 3, 64);
  #pragma unroll
  for (int r=0;r<4;r++) {
    float li = (r==0)?li0:(r==1)?li1:(r==2)?li2:li3;
    int q = qw + 4*g + r;
    #pragma unroll
    for (int dt=0;dt<4;dt++) {
      int d = dt*16 + q16;
      attnb[((size_t)(b*S_ + q))*D_ + h*DH_ + d] = f2bf(o[dt][r] * li);
    }
  }
}

// ---------------- output GEMM: out = attn @ Wo^T + bo ----------------
// 128x128 tile, BKO=64 swizzled LDS reads, 512 thr / 8 waves, 2-buffer
// pipeline; chunked XCD swizzle (256 blocks, 32/XCD: 4 A-panels + Wo < L2).
__global__ __launch_bounds__(512) void gemm_out(
    const ushort_t* __restrict__ Abf, const ushort_t* __restrict__ Bbf,
    const float* __restrict__ bias, float* __restrict__ out) {
  __shared__ __align__(16) ushort_t Al[2][128*BKO];
  __shared__ __align__(16) ushort_t Bl[2][128*BKO];
  int tid = threadIdx.x;
  int w = tid >> 6, lane = tid & 63;
  int g = lane >> 4, q16 = lane & 15;
  int wrow = (w >> 2) * 64, wcol = (w & 3) * 32;
  // chunked XCD swizzle: bid 0..255, 32 consecutive per XCD
  int bid = blockIdx.y * 8 + blockIdx.x;
  int swz = (bid & 7) * 32 + (bid >> 3);
  int m0 = (swz >> 3) * 128, n0 = (swz & 7) * 128;
  const int K = D_;
  const int nt = K / BKO;

  auto stageg = [&](int t, int buf) {
    int k0 = t * BKO;
    #pragma unroll
    for (int it = 0; it < 2; ++it) {
      int c = it*512 + tid;
      int row = c >> 3, scc = ((c & 7) ^ (row & 7)) * 8;
      gl_lds16(Abf + (size_t)(m0+row)*K + k0 + scc, &Al[buf][c*8]);
      gl_lds16(Bbf + (size_t)(n0+row)*K + k0 + scc, &Bl[buf][c*8]);
    }
  };

  f32x4 zero = {0.f,0.f,0.f,0.f};
  f32x4 acc[4][2];
  for (int i=0;i<4;i++) for (int j=0;j<2;j++) acc[i][j] = zero;

  stageg(0, 0);
  asm volatile("s_waitcnt vmcnt(0)" ::: "memory");
  __builtin_amdgcn_s_barrier();

  for (int t = 0; t < nt; ++t) {
    int cur = t & 1;
    if (t + 1 < nt) stageg(t + 1, cur ^ 1);
    #pragma unroll
    for (int kk = 0; kk < 2; ++kk) {
      bf16x8 af[4], bfr[2];
      #pragma unroll
      for (int i=0;i<4;i++) {
        int row = wrow + i*16 + q16;
        int slot = ((kk*4 + g) ^ (row & 7)) * 8;
        af[i] = *(const bf16x8*)(&Al[cur][row*BKO + slot]);
      }
      #pragma unroll
      for (int j=0;j<2;j++) {
        int row = wcol + j*16 + q16;
        int slot = ((kk*4 + g) ^ (row & 7)) * 8;
        bfr[j] = *(const bf16x8*)(&Bl[cur][row*BKO + slot]);
      }
      #pragma unroll
      for (int i=0;i<4;i++)
        #pragma unroll
        for (int j=0;j<2;j++)
          acc[i][j] = __builtin_amdgcn_mfma_f32_16x16x32_bf16(af[i], bfr[j], acc[i][j], 0, 0, 0);
    }
    asm volatile("s_waitcnt vmcnt(0)" ::: "memory");
    __builtin_amdgcn_s_barrier();
  }
  #pragma unroll
  for (int i=0;i<4;i++)
    #pragma unroll
    for (int j=0;j<2;j++)
      #pragma unroll
      for (int r=0;r<4;r++) {
        int gm = m0 + wrow + i*16 + g*4 + r;
        int gn = n0 + wcol + j*16 + q16;
        out[(size_t)gm*D_ + gn] = acc[i][j][r] + bias[gn];
      }
}

extern "C" void kernel_launch(void* const* d_in, const int* in_sizes, int n_in,
                              void* d_out, int out_size, void* d_ws, size_t ws_size,
                              hipStream_t stream) {
  const float* x  = (const float*)d_in[0];
  const float* Wi = (const float*)d_in[1];
  const float* bi = (const float*)d_in[2];
  const float* Wo = (const float*)d_in[3];
  const float* bo = (const float*)d_in[4];
  const int* causal = (const int*)d_in[5];
  float* out = (float*)d_out;

  ushort_t* xb   = (ushort_t*)d_ws;                       // 4096*1024 (reused as vtb)
  ushort_t* Wib  = xb  + (size_t)MTOT*D_;                 // 3072*1024
  ushort_t* Wob  = Wib + (size_t)NQKV*D_;                 // 1024*1024
  ushort_t* qbuf = Wob + (size_t)D_*D_;                   // 32*2048*64
  ushort_t* kbuf = qbuf + (size_t)B_*H_*S_*DH_;
  ushort_t* vbuf = kbuf + (size_t)B_*H_*S_*DH_;
  ushort_t* attnb = vbuf + (size_t)B_*H_*S_*DH_;          // 4096*1024
  ushort_t* vtb  = xb;  // xb dead after gemm_qkv; reuse for transposed V

  int ntot = CVN1 + CVN2 + CVN3;
  cvt_all<<<(ntot+255)/256, 256, 0, stream>>>(x, Wi, Wo, xb, Wib, Wob);

  gemm_qkv<<<dim3(NQKV/128, MTOT/128), 512, 0, stream>>>(xb, Wib, bi, qbuf, kbuf, vbuf);
  transpose_v<<<dim3(S_/64, B_*H_), 256, 0, stream>>>(vbuf, vtb);
  attn_fwd<<<1024, 256, 0, stream>>>(qbuf, kbuf, vtb, attnb, causal);
  gemm_out<<<dim3(D_/128, MTOT/128), 512, 0, stream>>>(attnb, Wob, bo, out);
}

// Round 20
// 113.710 us; speedup vs baseline: 1.1527x; 1.0014x over previous
//
#include <hip/hip_runtime.h>
#include <hip/hip_bf16.h>
#include <stdint.h>

#define B_    2
#define S_    2048
#define D_    1024
#define H_    16
#define DH_   64
#define MTOT  (B_*S_)     // 4096
#define NQKV  (3*D_)      // 3072

typedef __attribute__((ext_vector_type(8))) short  bf16x8;
typedef __attribute__((ext_vector_type(4))) short  bf16x4;
typedef __attribute__((ext_vector_type(4))) float  f32x4;
typedef __attribute__((ext_vector_type(8))) unsigned short u16x8;
typedef unsigned short ushort_t;

__device__ __forceinline__ ushort_t f2bf(float f) {
  union { float f; unsigned int i; } v; v.f = f;
  unsigned int r = v.i + 0x7FFF + ((v.i >> 16) & 1);
  return (ushort_t)(r >> 16);
}

__device__ __forceinline__ unsigned cvt_pk_bf16(float lo, float hi) {
  unsigned r;
  asm("v_cvt_pk_bf16_f32 %0, %1, %2" : "=v"(r) : "v"(lo), "v"(hi));
  return r;
}

__device__ __forceinline__ float fexp2(float x) {
  float r;
  asm("v_exp_f32 %0, %1" : "=v"(r) : "v"(x));
  return r;
}

// K=16 bf16 MFMA: builtin name differs across ROCm versions; chain with asm fallback.
#if __has_builtin(__builtin_amdgcn_mfma_f32_16x16x16_bf16)
__device__ __forceinline__ f32x4 mfma16(bf16x4 a, bf16x4 b, f32x4 c) {
  return __builtin_amdgcn_mfma_f32_16x16x16_bf16(a, b, c, 0, 0, 0);
}
#elif __has_builtin(__builtin_amdgcn_mfma_f32_16x16x16bf16_1k)
__device__ __forceinline__ f32x4 mfma16(bf16x4 a, bf16x4 b, f32x4 c) {
  return __builtin_amdgcn_mfma_f32_16x16x16bf16_1k(a, b, c, 0, 0, 0);
}
#else
__device__ __forceinline__ f32x4 mfma16(bf16x4 a, bf16x4 b, f32x4 c) {
  asm volatile("v_mfma_f32_16x16x16_bf16 %0, %1, %2, %0"
               : "+v"(c) : "v"(a), "v"(b));
  return c;
}
#endif

__device__ __forceinline__ void gl_lds16(const ushort_t* g, ushort_t* l) {
  __builtin_amdgcn_global_load_lds(
      (const __attribute__((address_space(1))) unsigned int*)g,
      (__attribute__((address_space(3))) unsigned int*)l, 16, 0, 0);
}

// ---------------- fused fp32 -> bf16 conversion (x, Wi, Wo) ----------------
#define CVN1 (MTOT*D_/8)
#define CVN2 (NQKV*D_/8)
#define CVN3 (D_*D_/8)
__global__ __launch_bounds__(256) void cvt_all(
    const float* __restrict__ x, const float* __restrict__ Wi, const float* __restrict__ Wo,
    ushort_t* __restrict__ xb, ushort_t* __restrict__ Wib, ushort_t* __restrict__ Wob) {
  int i = blockIdx.x * blockDim.x + threadIdx.x;
  const float* src; ushort_t* dst; int k;
  if (i < CVN1)            { src = x;  dst = xb;  k = i; }
  else if (i < CVN1+CVN2)  { src = Wi; dst = Wib; k = i - CVN1; }
  else                     { src = Wo; dst = Wob; k = i - CVN1 - CVN2; }
  const float4* s4 = (const float4*)src;
  float4 a = s4[2*k], b = s4[2*k+1];
  u16x8 o;
  o[0]=f2bf(a.x); o[1]=f2bf(a.y); o[2]=f2bf(a.z); o[3]=f2bf(a.w);
  o[4]=f2bf(b.x); o[5]=f2bf(b.y); o[6]=f2bf(b.z); o[7]=f2bf(b.w);
  ((u16x8*)dst)[k] = o;
}

// ---------------- QKV GEMM: qkv = x @ Wi^T + bi ----------------
// gemm_out structure: 512 thr / 8 waves (2Mx4N, 64x32/wave), BK=64 swizzled,
// 2-buffer raw-barrier pipeline; chunked XCD swizzle; q/k/v scatter epilogue.
#define BKO 64
// scale folded into q: 1/sqrt(64) * log2(e)  (exp2-domain softmax)
#define QSCALE 0.18033688011112042f
__global__ __launch_bounds__(512) void gemm_qkv(
    const ushort_t* __restrict__ Abf, const ushort_t* __restrict__ Bbf,
    const float* __restrict__ bias,
    ushort_t* __restrict__ qb, ushort_t* __restrict__ kb, ushort_t* __restrict__ vb) {
  __shared__ __align__(16) ushort_t Al[2][128*BKO];
  __shared__ __align__(16) ushort_t Bl[2][128*BKO];
  int tid = threadIdx.x;
  int w = tid >> 6, lane = tid & 63;
  int g = lane >> 4, q16 = lane & 15;
  int wrow = (w >> 2) * 64, wcol = (w & 3) * 32;
  int bid = blockIdx.y * 24 + blockIdx.x;
  int swz = (bid & 7) * 96 + (bid >> 3);
  int m0 = (swz / 24) * 128, n0 = (swz % 24) * 128;
  const int K = D_;
  const int nt = K / BKO;

  auto stageg = [&](int t, int buf) {
    int k0 = t * BKO;
    #pragma unroll
    for (int it = 0; it < 2; ++it) {
      int c = it*512 + tid;
      int row = c >> 3, scc = ((c & 7) ^ (row & 7)) * 8;
      gl_lds16(Abf + (size_t)(m0+row)*K + k0 + scc, &Al[buf][c*8]);
      gl_lds16(Bbf + (size_t)(n0+row)*K + k0 + scc, &Bl[buf][c*8]);
    }
  };

  f32x4 zero = {0.f,0.f,0.f,0.f};
  f32x4 acc[4][2];
  for (int i=0;i<4;i++) for (int j=0;j<2;j++) acc[i][j] = zero;

  stageg(0, 0);
  asm volatile("s_waitcnt vmcnt(0)" ::: "memory");
  __builtin_amdgcn_s_barrier();

  for (int t = 0; t < nt; ++t) {
    int cur = t & 1;
    if (t + 1 < nt) stageg(t + 1, cur ^ 1);
    #pragma unroll
    for (int kk = 0; kk < 2; ++kk) {
      bf16x8 af[4], bfr[2];
      #pragma unroll
      for (int i=0;i<4;i++) {
        int row = wrow + i*16 + q16;
        int slot = ((kk*4 + g) ^ (row & 7)) * 8;
        af[i] = *(const bf16x8*)(&Al[cur][row*BKO + slot]);
      }
      #pragma unroll
      for (int j=0;j<2;j++) {
        int row = wcol + j*16 + q16;
        int slot = ((kk*4 + g) ^ (row & 7)) * 8;
        bfr[j] = *(const bf16x8*)(&Bl[cur][row*BKO + slot]);
      }
      #pragma unroll
      for (int i=0;i<4;i++)
        #pragma unroll
        for (int j=0;j<2;j++)
          acc[i][j] = __builtin_amdgcn_mfma_f32_16x16x32_bf16(af[i], bfr[j], acc[i][j], 0, 0, 0);
    }
    asm volatile("s_waitcnt vmcnt(0)" ::: "memory");
    __builtin_amdgcn_s_barrier();
  }
  #pragma unroll
  for (int i=0;i<4;i++)
    #pragma unroll
    for (int j=0;j<2;j++)
      #pragma unroll
      for (int r=0;r<4;r++) {
        int gm = m0 + wrow + i*16 + g*4 + r;
        int gn = n0 + wcol + j*16 + q16;
        float v = acc[i][j][r] + bias[gn];
        int b = gm >> 11, s = gm & (S_-1);
        int sect = gn >> 10, hn = gn & (D_-1);
        int hh = hn >> 6, d = hn & 63;
        size_t idx = (((size_t)(b*H_ + hh))*S_ + s)*DH_ + d;
        if (sect == 0) v *= QSCALE;
        ushort_t val = f2bf(v);
        if (sect == 0) qb[idx] = val;
        else if (sect == 1) kb[idx] = val;
        else vb[idx] = val;
      }
}

// ---------------- V transpose: [BH][S][DH] -> [BH][DH][S] ----------------
__global__ __launch_bounds__(256) void transpose_v(
    const ushort_t* __restrict__ vb, ushort_t* __restrict__ vtb) {
  __shared__ ushort_t T[64*72];
  int bh = blockIdx.y;
  int s0 = blockIdx.x * 64;
  int tid = threadIdx.x;
  const ushort_t* src = vb + (size_t)bh * S_ * DH_;
  ushort_t* dst = vtb + (size_t)bh * DH_ * S_;
  for (int it = 0; it < 2; ++it) {
    int c = it*256 + tid;
    int row = c >> 3, cc = c & 7;
    *(uint4*)&T[row*72 + cc*8] = *(const uint4*)(src + (size_t)(s0+row)*DH_ + cc*8);
  }
  __syncthreads();
  for (int it = 0; it < 2; ++it) {
    int c = it*256 + tid;
    int d = c >> 3, sc = c & 7;
    u16x8 o;
    #pragma unroll
    for (int e = 0; e < 8; ++e) o[e] = T[(sc*8+e)*72 + d];
    *(u16x8*)(dst + (size_t)d*S_ + s0 + sc*8) = o;
  }
}

// ---------------- flash attention v9 (best measured) ----------------
// 1024 blocks x 4 waves; 64-row q-blocks, 16 rows/wave; 2-buffer KV (32 KB);
// boustrophedon qblk map (equal per-CU totals); XCD-grouped bh; in-lane K=16 PV.
#define KVB 64
#define DTHR 8.0f
__global__ __launch_bounds__(256) void attn_fwd(
    const ushort_t* __restrict__ qb, const ushort_t* __restrict__ kb,
    const ushort_t* __restrict__ vtb, ushort_t* __restrict__ attnb,
    const int* __restrict__ causal) {
  int wg = blockIdx.x;                  // 0..1023
  int xcd = wg & 7;
  int j = wg >> 3;                      // 0..127 per-XCD dispatch sequence
  int v = j >> 5;                       // visit 0..3
  int u = j & 31;                       // CU slot within XCD
  int a = u >> 2;                       // qblk subgroup 0..7
  int qi = v*8 + ((v & 1) ? (7 - a) : a);   // boustrophedon: per-CU sums equal
  int qblk = 31 - qi;
  int bh = (u & 3) * 8 + xcd;           // 4 bh per XCD -> KV L2-resident
  int b = bh >> 4, h = bh & 15;
  int tid = threadIdx.x, w = tid >> 6, lane = tid & 63;
  int g = lane >> 4, q16 = lane & 15;
  const ushort_t* qh  = qb  + (size_t)bh * S_ * DH_;
  const ushort_t* kh  = kb  + (size_t)bh * S_ * DH_;
  const ushort_t* vth = vtb + (size_t)bh * DH_ * S_;
  __shared__ __align__(16) ushort_t Kl[2][KVB*64];
  __shared__ __align__(16) ushort_t Vtl[2][64*KVB];
  bool use_causal = (causal[0] != 0);

  int nkv = use_causal ? (qblk + 1) : (S_/KVB);
  int qw = qblk*64 + w*16;

  bf16x8 qc0 = *(const bf16x8*)(qh + (size_t)(qw + q16)*DH_ +  0 + g*8);
  bf16x8 qc1 = *(const bf16x8*)(qh + (size_t)(qw + q16)*DH_ + 32 + g*8);

  int c0 = tid, c1 = tid + 256;
  int r0 = c0 >> 3, sw0 = ((c0 & 7) ^ (r0 & 7)) * 8;
  int r1 = c1 >> 3, sw1 = ((c1 & 7) ^ (r1 & 7)) * 8;
  const ushort_t* kp0 = kh + r0*DH_ + sw0;
  const ushort_t* kp1 = kh + r1*DH_ + sw1;
  const ushort_t* vp0 = vth + (size_t)r0*S_ + sw0;
  const ushort_t* vp1 = vth + (size_t)r1*S_ + sw1;

  auto stage = [&](int t, int buf) {
    size_t kadv = (size_t)(t*KVB) * DH_;
    int vadv = t*KVB;
    gl_lds16(kp0 + kadv, &Kl[buf][c0*8]);
    gl_lds16(kp1 + kadv, &Kl[buf][c1*8]);
    gl_lds16(vp0 + vadv, &Vtl[buf][c0*8]);
    gl_lds16(vp1 + vadv, &Vtl[buf][c1*8]);
  };

  f32x4 zero = {0.f,0.f,0.f,0.f};
  f32x4 o[4];
  #pragma unroll
  for (int dt=0;dt<4;dt++) o[dt] = zero;
  float mrun = -1e30f, lrun = 0.f;

  stage(0, 0);
  asm volatile("s_waitcnt vmcnt(0)" ::: "memory");
  __builtin_amdgcn_s_barrier();

  for (int it = 0; it < nkv; ++it) {
    int cur = it & 1;
    int kvbase = it * KVB;
    if (it + 1 < nkv) stage(it + 1, cur ^ 1);   // lands during compute below

    f32x4 sacc[4];
    #pragma unroll
    for (int j2=0;j2<4;j2++) sacc[j2] = zero;
    #pragma unroll
    for (int kk=0;kk<2;kk++) {
      bf16x8 qf = kk ? qc1 : qc0;
      #pragma unroll
      for (int j2=0;j2<4;j2++) {
        int row = j2*16 + q16;
        int slot = (kk*4 + g) ^ (row & 7);
        bf16x8 kf = *(const bf16x8*)(&Kl[cur][row*64 + slot*8]);
        sacc[j2] = __builtin_amdgcn_mfma_f32_16x16x32_bf16(kf, qf, sacc[j2], 0, 0, 0);
      }
    }
    if (use_causal && kvbase + KVB - 1 > qw) {
      int qd = qw + q16 - kvbase;
      #pragma unroll
      for (int j2=0;j2<4;j2++)
        #pragma unroll
        for (int r=0;r<4;r++)
          if (16*j2 + 4*g + r > qd) sacc[j2][r] = -1e30f;
    }
    float m0v = fmaxf(fmaxf(sacc[0][0], sacc[0][1]), fmaxf(sacc[0][2], sacc[0][3]));
    float m1v = fmaxf(fmaxf(sacc[1][0], sacc[1][1]), fmaxf(sacc[1][2], sacc[1][3]));
    float m2v = fmaxf(fmaxf(sacc[2][0], sacc[2][1]), fmaxf(sacc[2][2], sacc[2][3]));
    float m3v = fmaxf(fmaxf(sacc[3][0], sacc[3][1]), fmaxf(sacc[3][2], sacc[3][3]));
    float mx = fmaxf(fmaxf(m0v, m1v), fmaxf(m2v, m3v));
    mx = fmaxf(mx, __shfl_xor(mx, 16, 64));
    mx = fmaxf(mx, __shfl_xor(mx, 32, 64));
    if (!__all(mx - mrun <= DTHR)) {
      float mnew = fmaxf(mrun, mx);
      float alpha = fexp2(mrun - mnew);
      lrun *= alpha;
      float av0 = __shfl(alpha, 4*g + 0, 64);
      float av1 = __shfl(alpha, 4*g + 1, 64);
      float av2 = __shfl(alpha, 4*g + 2, 64);
      float av3 = __shfl(alpha, 4*g + 3, 64);
      #pragma unroll
      for (int dt=0;dt<4;dt++) {
        o[dt][0] *= av0; o[dt][1] *= av1; o[dt][2] *= av2; o[dt][3] *= av3;
      }
      mrun = mnew;
    }
    float p[4][4];
    float rs = 0.f;
    #pragma unroll
    for (int j2=0;j2<4;j2++)
      #pragma unroll
      for (int r=0;r<4;r++) {
        p[j2][r] = fexp2(sacc[j2][r] - mrun);
        rs += p[j2][r];
      }
    rs += __shfl_xor(rs, 16, 64);
    rs += __shfl_xor(rs, 32, 64);
    lrun += rs;
    #pragma unroll
    for (int s=0;s<4;s++) {
      union { unsigned u2[2]; bf16x4 v2; } pk;
      pk.u2[0] = cvt_pk_bf16(p[s][0], p[s][1]);
      pk.u2[1] = cvt_pk_bf16(p[s][2], p[s][3]);
      int E = 16*s + 4*g;
      #pragma unroll
      for (int dt=0;dt<4;dt++) {
        int row = dt*16 + q16;
        int off = row*64 + ((E >> 3) ^ (row & 7))*8 + (E & 7);
        bf16x4 vf = *(const bf16x4*)(&Vtl[cur][off]);
        o[dt] = mfma16(pk.v2, vf, o[dt]);
      }
    }
    asm volatile("s_waitcnt vmcnt(0)" ::: "memory");
    __builtin_amdgcn_s_barrier();
  }
  float li0 = 1.f / __shfl(lrun, 4*g + 0, 64);
  float li1 = 1.f / __shfl(lrun, 4*g + 1, 64);
  float li2 = 1.f / __shfl(lrun, 4*g + 2, 64);
  float li3 = 1.f / __shfl(lrun, 4*g + 3, 64);
  #pragma unroll
  for (int r=0;r<4;r++) {
    float li = (r==0)?li0:(r==1)?li1:(r==2)?li2:li3;
    int q = qw + 4*g + r;
    #pragma unroll
    for (int dt=0;dt<4;dt++) {
      int d = dt*16 + q16;
      attnb[((size_t)(b*S_ + q))*D_ + h*DH_ + d] = f2bf(o[dt][r] * li);
    }
  }
}

// ---------------- output GEMM: out = attn @ Wo^T + bo ----------------
// 128x128 tile, BKO=64 swizzled LDS reads, 512 thr / 8 waves, 2-buffer
// pipeline; chunked XCD swizzle (256 blocks, 32/XCD: 4 A-panels + Wo < L2).
__global__ __launch_bounds__(512) void gemm_out(
    const ushort_t* __restrict__ Abf, const ushort_t* __restrict__ Bbf,
    const float* __restrict__ bias, float* __restrict__ out) {
  __shared__ __align__(16) ushort_t Al[2][128*BKO];
  __shared__ __align__(16) ushort_t Bl[2][128*BKO];
  int tid = threadIdx.x;
  int w = tid >> 6, lane = tid & 63;
  int g = lane >> 4, q16 = lane & 15;
  int wrow = (w >> 2) * 64, wcol = (w & 3) * 32;
  int bid = blockIdx.y * 8 + blockIdx.x;
  int swz = (bid & 7) * 32 + (bid >> 3);
  int m0 = (swz >> 3) * 128, n0 = (swz & 7) * 128;
  const int K = D_;
  const int nt = K / BKO;

  auto stageg = [&](int t, int buf) {
    int k0 = t * BKO;
    #pragma unroll
    for (int it = 0; it < 2; ++it) {
      int c = it*512 + tid;
      int row = c >> 3, scc = ((c & 7) ^ (row & 7)) * 8;
      gl_lds16(Abf + (size_t)(m0+row)*K + k0 + scc, &Al[buf][c*8]);
      gl_lds16(Bbf + (size_t)(n0+row)*K + k0 + scc, &Bl[buf][c*8]);
    }
  };

  f32x4 zero = {0.f,0.f,0.f,0.f};
  f32x4 acc[4][2];
  for (int i=0;i<4;i++) for (int j=0;j<2;j++) acc[i][j] = zero;

  stageg(0, 0);
  asm volatile("s_waitcnt vmcnt(0)" ::: "memory");
  __builtin_amdgcn_s_barrier();

  for (int t = 0; t < nt; ++t) {
    int cur = t & 1;
    if (t + 1 < nt) stageg(t + 1, cur ^ 1);
    #pragma unroll
    for (int kk = 0; kk < 2; ++kk) {
      bf16x8 af[4], bfr[2];
      #pragma unroll
      for (int i=0;i<4;i++) {
        int row = wrow + i*16 + q16;
        int slot = ((kk*4 + g) ^ (row & 7)) * 8;
        af[i] = *(const bf16x8*)(&Al[cur][row*BKO + slot]);
      }
      #pragma unroll
      for (int j=0;j<2;j++) {
        int row = wcol + j*16 + q16;
        int slot = ((kk*4 + g) ^ (row & 7)) * 8;
        bfr[j] = *(const bf16x8*)(&Bl[cur][row*BKO + slot]);
      }
      #pragma unroll
      for (int i=0;i<4;i++)
        #pragma unroll
        for (int j=0;j<2;j++)
          acc[i][j] = __builtin_amdgcn_mfma_f32_16x16x32_bf16(af[i], bfr[j], acc[i][j], 0, 0, 0);
    }
    asm volatile("s_waitcnt vmcnt(0)" ::: "memory");
    __builtin_amdgcn_s_barrier();
  }
  #pragma unroll
  for (int i=0;i<4;i++)
    #pragma unroll
    for (int j=0;j<2;j++)
      #pragma unroll
      for (int r=0;r<4;r++) {
        int gm = m0 + wrow + i*16 + g*4 + r;
        int gn = n0 + wcol + j*16 + q16;
        out[(size_t)gm*D_ + gn] = acc[i][j][r] + bias[gn];
      }
}

extern "C" void kernel_launch(void* const* d_in, const int* in_sizes, int n_in,
                              void* d_out, int out_size, void* d_ws, size_t ws_size,
                              hipStream_t stream) {
  const float* x  = (const float*)d_in[0];
  const float* Wi = (const float*)d_in[1];
  const float* bi = (const float*)d_in[2];
  const float* Wo = (const float*)d_in[3];
  const float* bo = (const float*)d_in[4];
  const int* causal = (const int*)d_in[5];
  float* out = (float*)d_out;

  ushort_t* xb   = (ushort_t*)d_ws;                       // 4096*1024 (reused as vtb)
  ushort_t* Wib  = xb  + (size_t)MTOT*D_;                 // 3072*1024
  ushort_t* Wob  = Wib + (size_t)NQKV*D_;                 // 1024*1024
  ushort_t* qbuf = Wob + (size_t)D_*D_;                   // 32*2048*64
  ushort_t* kbuf = qbuf + (size_t)B_*H_*S_*DH_;
  ushort_t* vbuf = kbuf + (size_t)B_*H_*S_*DH_;
  ushort_t* attnb = vbuf + (size_t)B_*H_*S_*DH_;          // 4096*1024
  ushort_t* vtb  = xb;  // xb dead after gemm_qkv; reuse for transposed V

  int ntot = CVN1 + CVN2 + CVN3;
  cvt_all<<<(ntot+255)/256, 256, 0, stream>>>(x, Wi, Wo, xb, Wib, Wob);

  gemm_qkv<<<dim3(NQKV/128, MTOT/128), 512, 0, stream>>>(xb, Wib, bi, qbuf, kbuf, vbuf);
  transpose_v<<<dim3(S_/64, B_*H_), 256, 0, stream>>>(vbuf, vtb);
  attn_fwd<<<1024, 256, 0, stream>>>(qbuf, kbuf, vtb, attnb, causal);
  gemm_out<<<dim3(D_/128, MTOT/128), 512, 0, stream>>>(attnb, Wob, bo, out);
}

// Round 21
// 109.189 us; speedup vs baseline: 1.2005x; 1.0414x over previous
//
#include <hip/hip_runtime.h>
#include <hip/hip_bf16.h>
#include <stdint.h>

#define B_    2
#define S_    2048
#define D_    1024
#define H_    16
#define DH_   64
#define MTOT  (B_*S_)     // 4096
#define NQKV  (3*D_)      // 3072

typedef __attribute__((ext_vector_type(8))) short  bf16x8;
typedef __attribute__((ext_vector_type(4))) short  bf16x4;
typedef __attribute__((ext_vector_type(4))) float  f32x4;
typedef __attribute__((ext_vector_type(8))) unsigned short u16x8;
typedef unsigned short ushort_t;

__device__ __forceinline__ ushort_t f2bf(float f) {
  union { float f; unsigned int i; } v; v.f = f;
  unsigned int r = v.i + 0x7FFF + ((v.i >> 16) & 1);
  return (ushort_t)(r >> 16);
}

__device__ __forceinline__ unsigned cvt_pk_bf16(float lo, float hi) {
  unsigned r;
  asm("v_cvt_pk_bf16_f32 %0, %1, %2" : "=v"(r) : "v"(lo), "v"(hi));
  return r;
}

__device__ __forceinline__ float fexp2(float x) {
  float r;
  asm("v_exp_f32 %0, %1" : "=v"(r) : "v"(x));
  return r;
}

// K=16 bf16 MFMA: builtin name differs across ROCm versions; chain with asm fallback.
#if __has_builtin(__builtin_amdgcn_mfma_f32_16x16x16_bf16)
__device__ __forceinline__ f32x4 mfma16(bf16x4 a, bf16x4 b, f32x4 c) {
  return __builtin_amdgcn_mfma_f32_16x16x16_bf16(a, b, c, 0, 0, 0);
}
#elif __has_builtin(__builtin_amdgcn_mfma_f32_16x16x16bf16_1k)
__device__ __forceinline__ f32x4 mfma16(bf16x4 a, bf16x4 b, f32x4 c) {
  return __builtin_amdgcn_mfma_f32_16x16x16bf16_1k(a, b, c, 0, 0, 0);
}
#else
__device__ __forceinline__ f32x4 mfma16(bf16x4 a, bf16x4 b, f32x4 c) {
  asm volatile("v_mfma_f32_16x16x16_bf16 %0, %1, %2, %0"
               : "+v"(c) : "v"(a), "v"(b));
  return c;
}
#endif

__device__ __forceinline__ void gl_lds16(const ushort_t* g, ushort_t* l) {
  __builtin_amdgcn_global_load_lds(
      (const __attribute__((address_space(1))) unsigned int*)g,
      (__attribute__((address_space(3))) unsigned int*)l, 16, 0, 0);
}

// ---------------- fused fp32 -> bf16 conversion (x, Wi, Wo) ----------------
#define CVN1 (MTOT*D_/8)
#define CVN2 (NQKV*D_/8)
#define CVN3 (D_*D_/8)
__global__ __launch_bounds__(256) void cvt_all(
    const float* __restrict__ x, const float* __restrict__ Wi, const float* __restrict__ Wo,
    ushort_t* __restrict__ xb, ushort_t* __restrict__ Wib, ushort_t* __restrict__ Wob) {
  int i = blockIdx.x * blockDim.x + threadIdx.x;
  const float* src; ushort_t* dst; int k;
  if (i < CVN1)            { src = x;  dst = xb;  k = i; }
  else if (i < CVN1+CVN2)  { src = Wi; dst = Wib; k = i - CVN1; }
  else                     { src = Wo; dst = Wob; k = i - CVN1 - CVN2; }
  const float4* s4 = (const float4*)src;
  float4 a = s4[2*k], b = s4[2*k+1];
  u16x8 o;
  o[0]=f2bf(a.x); o[1]=f2bf(a.y); o[2]=f2bf(a.z); o[3]=f2bf(a.w);
  o[4]=f2bf(b.x); o[5]=f2bf(b.y); o[6]=f2bf(b.z); o[7]=f2bf(b.w);
  ((u16x8*)dst)[k] = o;
}

// ---------------- QKV GEMM: qkv = x @ Wi^T + bi ----------------
// gemm_out structure: 512 thr / 8 waves (2Mx4N, 64x32/wave), BK=64 swizzled,
// 2-buffer raw-barrier pipeline; chunked XCD swizzle; q/k/v scatter epilogue.
#define BKO 64
// scale folded into q: 1/sqrt(64) * log2(e)  (exp2-domain softmax)
#define QSCALE 0.18033688011112042f
__global__ __launch_bounds__(512) void gemm_qkv(
    const ushort_t* __restrict__ Abf, const ushort_t* __restrict__ Bbf,
    const float* __restrict__ bias,
    ushort_t* __restrict__ qb, ushort_t* __restrict__ kb, ushort_t* __restrict__ vb) {
  __shared__ __align__(16) ushort_t Al[2][128*BKO];
  __shared__ __align__(16) ushort_t Bl[2][128*BKO];
  int tid = threadIdx.x;
  int w = tid >> 6, lane = tid & 63;
  int g = lane >> 4, q16 = lane & 15;
  int wrow = (w >> 2) * 64, wcol = (w & 3) * 32;
  int bid = blockIdx.y * 24 + blockIdx.x;
  int swz = (bid & 7) * 96 + (bid >> 3);
  int m0 = (swz / 24) * 128, n0 = (swz % 24) * 128;
  const int K = D_;
  const int nt = K / BKO;

  auto stageg = [&](int t, int buf) {
    int k0 = t * BKO;
    #pragma unroll
    for (int it = 0; it < 2; ++it) {
      int c = it*512 + tid;
      int row = c >> 3, scc = ((c & 7) ^ (row & 7)) * 8;
      gl_lds16(Abf + (size_t)(m0+row)*K + k0 + scc, &Al[buf][c*8]);
      gl_lds16(Bbf + (size_t)(n0+row)*K + k0 + scc, &Bl[buf][c*8]);
    }
  };

  f32x4 zero = {0.f,0.f,0.f,0.f};
  f32x4 acc[4][2];
  for (int i=0;i<4;i++) for (int j=0;j<2;j++) acc[i][j] = zero;

  stageg(0, 0);
  asm volatile("s_waitcnt vmcnt(0)" ::: "memory");
  __builtin_amdgcn_s_barrier();

  for (int t = 0; t < nt; ++t) {
    int cur = t & 1;
    if (t + 1 < nt) stageg(t + 1, cur ^ 1);
    #pragma unroll
    for (int kk = 0; kk < 2; ++kk) {
      bf16x8 af[4], bfr[2];
      #pragma unroll
      for (int i=0;i<4;i++) {
        int row = wrow + i*16 + q16;
        int slot = ((kk*4 + g) ^ (row & 7)) * 8;
        af[i] = *(const bf16x8*)(&Al[cur][row*BKO + slot]);
      }
      #pragma unroll
      for (int j=0;j<2;j++) {
        int row = wcol + j*16 + q16;
        int slot = ((kk*4 + g) ^ (row & 7)) * 8;
        bfr[j] = *(const bf16x8*)(&Bl[cur][row*BKO + slot]);
      }
      #pragma unroll
      for (int i=0;i<4;i++)
        #pragma unroll
        for (int j=0;j<2;j++)
          acc[i][j] = __builtin_amdgcn_mfma_f32_16x16x32_bf16(af[i], bfr[j], acc[i][j], 0, 0, 0);
    }
    asm volatile("s_waitcnt vmcnt(0)" ::: "memory");
    __builtin_amdgcn_s_barrier();
  }
  #pragma unroll
  for (int i=0;i<4;i++)
    #pragma unroll
    for (int j=0;j<2;j++)
      #pragma unroll
      for (int r=0;r<4;r++) {
        int gm = m0 + wrow + i*16 + g*4 + r;
        int gn = n0 + wcol + j*16 + q16;
        float v = acc[i][j][r] + bias[gn];
        int b = gm >> 11, s = gm & (S_-1);
        int sect = gn >> 10, hn = gn & (D_-1);
        int hh = hn >> 6, d = hn & 63;
        size_t idx = (((size_t)(b*H_ + hh))*S_ + s)*DH_ + d;
        if (sect == 0) v *= QSCALE;
        ushort_t val = f2bf(v);
        if (sect == 0) qb[idx] = val;
        else if (sect == 1) kb[idx] = val;
        else vb[idx] = val;
      }
}

// ---------------- V transpose: [BH][S][DH] -> [BH][DH][S] ----------------
__global__ __launch_bounds__(256) void transpose_v(
    const ushort_t* __restrict__ vb, ushort_t* __restrict__ vtb) {
  __shared__ ushort_t T[64*72];
  int bh = blockIdx.y;
  int s0 = blockIdx.x * 64;
  int tid = threadIdx.x;
  const ushort_t* src = vb + (size_t)bh * S_ * DH_;
  ushort_t* dst = vtb + (size_t)bh * DH_ * S_;
  for (int it = 0; it < 2; ++it) {
    int c = it*256 + tid;
    int row = c >> 3, cc = c & 7;
    *(uint4*)&T[row*72 + cc*8] = *(const uint4*)(src + (size_t)(s0+row)*DH_ + cc*8);
  }
  __syncthreads();
  for (int it = 0; it < 2; ++it) {
    int c = it*256 + tid;
    int d = c >> 3, sc = c & 7;
    u16x8 o;
    #pragma unroll
    for (int e = 0; e < 8; ++e) o[e] = T[(sc*8+e)*72 + d];
    *(u16x8*)(dst + (size_t)d*S_ + s0 + sc*8) = o;
  }
}

// ---------------- flash attention v12: lazy cross-lane max ----------------
// v9 + defer-max test on PER-LANE local max (no shuffles in common path);
// cross-lane max computed only inside the rescale branch. Bound preserved:
// every elem <= local_max <= mrun + THR => p <= 2^THR; mrun stays uniform
// across each q-row's 4-lane group (rescale path reduces globally as before).
#define KVB 64
#define DTHR 8.0f
__global__ __launch_bounds__(256) void attn_fwd(
    const ushort_t* __restrict__ qb, const ushort_t* __restrict__ kb,
    const ushort_t* __restrict__ vtb, ushort_t* __restrict__ attnb,
    const int* __restrict__ causal) {
  int wg = blockIdx.x;                  // 0..1023
  int xcd = wg & 7;
  int j = wg >> 3;                      // 0..127 per-XCD dispatch sequence
  int v = j >> 5;                       // visit 0..3
  int u = j & 31;                       // CU slot within XCD
  int a = u >> 2;                       // qblk subgroup 0..7
  int qi = v*8 + ((v & 1) ? (7 - a) : a);   // boustrophedon: per-CU sums equal
  int qblk = 31 - qi;
  int bh = (u & 3) * 8 + xcd;           // 4 bh per XCD -> KV L2-resident
  int b = bh >> 4, h = bh & 15;
  int tid = threadIdx.x, w = tid >> 6, lane = tid & 63;
  int g = lane >> 4, q16 = lane & 15;
  const ushort_t* qh  = qb  + (size_t)bh * S_ * DH_;
  const ushort_t* kh  = kb  + (size_t)bh * S_ * DH_;
  const ushort_t* vth = vtb + (size_t)bh * DH_ * S_;
  __shared__ __align__(16) ushort_t Kl[2][KVB*64];
  __shared__ __align__(16) ushort_t Vtl[2][64*KVB];
  bool use_causal = (causal[0] != 0);

  int nkv = use_causal ? (qblk + 1) : (S_/KVB);
  int qw = qblk*64 + w*16;

  bf16x8 qc0 = *(const bf16x8*)(qh + (size_t)(qw + q16)*DH_ +  0 + g*8);
  bf16x8 qc1 = *(const bf16x8*)(qh + (size_t)(qw + q16)*DH_ + 32 + g*8);

  int c0 = tid, c1 = tid + 256;
  int r0 = c0 >> 3, sw0 = ((c0 & 7) ^ (r0 & 7)) * 8;
  int r1 = c1 >> 3, sw1 = ((c1 & 7) ^ (r1 & 7)) * 8;
  const ushort_t* kp0 = kh + r0*DH_ + sw0;
  const ushort_t* kp1 = kh + r1*DH_ + sw1;
  const ushort_t* vp0 = vth + (size_t)r0*S_ + sw0;
  const ushort_t* vp1 = vth + (size_t)r1*S_ + sw1;

  auto stage = [&](int t, int buf) {
    size_t kadv = (size_t)(t*KVB) * DH_;
    int vadv = t*KVB;
    gl_lds16(kp0 + kadv, &Kl[buf][c0*8]);
    gl_lds16(kp1 + kadv, &Kl[buf][c1*8]);
    gl_lds16(vp0 + vadv, &Vtl[buf][c0*8]);
    gl_lds16(vp1 + vadv, &Vtl[buf][c1*8]);
  };

  f32x4 zero = {0.f,0.f,0.f,0.f};
  f32x4 o[4];
  #pragma unroll
  for (int dt=0;dt<4;dt++) o[dt] = zero;
  float mrun = -1e30f, lrun = 0.f;

  stage(0, 0);
  asm volatile("s_waitcnt vmcnt(0)" ::: "memory");
  __builtin_amdgcn_s_barrier();

  for (int it = 0; it < nkv; ++it) {
    int cur = it & 1;
    int kvbase = it * KVB;
    if (it + 1 < nkv) stage(it + 1, cur ^ 1);   // lands during compute below

    f32x4 sacc[4];
    #pragma unroll
    for (int j2=0;j2<4;j2++) sacc[j2] = zero;
    #pragma unroll
    for (int kk=0;kk<2;kk++) {
      bf16x8 qf = kk ? qc1 : qc0;
      #pragma unroll
      for (int j2=0;j2<4;j2++) {
        int row = j2*16 + q16;
        int slot = (kk*4 + g) ^ (row & 7);
        bf16x8 kf = *(const bf16x8*)(&Kl[cur][row*64 + slot*8]);
        sacc[j2] = __builtin_amdgcn_mfma_f32_16x16x32_bf16(kf, qf, sacc[j2], 0, 0, 0);
      }
    }
    if (use_causal && kvbase + KVB - 1 > qw) {
      int qd = qw + q16 - kvbase;
      #pragma unroll
      for (int j2=0;j2<4;j2++)
        #pragma unroll
        for (int r=0;r<4;r++)
          if (16*j2 + 4*g + r > qd) sacc[j2][r] = -1e30f;
    }
    // ---- lazy cross-lane max: shuffle-free defer test on local max ----
    float m0v = fmaxf(fmaxf(sacc[0][0], sacc[0][1]), fmaxf(sacc[0][2], sacc[0][3]));
    float m1v = fmaxf(fmaxf(sacc[1][0], sacc[1][1]), fmaxf(sacc[1][2], sacc[1][3]));
    float m2v = fmaxf(fmaxf(sacc[2][0], sacc[2][1]), fmaxf(sacc[2][2], sacc[2][3]));
    float m3v = fmaxf(fmaxf(sacc[3][0], sacc[3][1]), fmaxf(sacc[3][2], sacc[3][3]));
    float lmx = fmaxf(fmaxf(m0v, m1v), fmaxf(m2v, m3v));
    if (!__all(lmx - mrun <= DTHR)) {
      float mx = fmaxf(lmx, __shfl_xor(lmx, 16, 64));
      mx = fmaxf(mx, __shfl_xor(mx, 32, 64));
      float mnew = fmaxf(mrun, mx);
      float alpha = fexp2(mrun - mnew);
      lrun *= alpha;
      float av0 = __shfl(alpha, 4*g + 0, 64);
      float av1 = __shfl(alpha, 4*g + 1, 64);
      float av2 = __shfl(alpha, 4*g + 2, 64);
      float av3 = __shfl(alpha, 4*g + 3, 64);
      #pragma unroll
      for (int dt=0;dt<4;dt++) {
        o[dt][0] *= av0; o[dt][1] *= av1; o[dt][2] *= av2; o[dt][3] *= av3;
      }
      mrun = mnew;
    }
    float p[4][4];
    float rs = 0.f;
    #pragma unroll
    for (int j2=0;j2<4;j2++)
      #pragma unroll
      for (int r=0;r<4;r++) {
        p[j2][r] = fexp2(sacc[j2][r] - mrun);
        rs += p[j2][r];
      }
    rs += __shfl_xor(rs, 16, 64);
    rs += __shfl_xor(rs, 32, 64);
    lrun += rs;
    #pragma unroll
    for (int s=0;s<4;s++) {
      union { unsigned u2[2]; bf16x4 v2; } pk;
      pk.u2[0] = cvt_pk_bf16(p[s][0], p[s][1]);
      pk.u2[1] = cvt_pk_bf16(p[s][2], p[s][3]);
      int E = 16*s + 4*g;
      #pragma unroll
      for (int dt=0;dt<4;dt++) {
        int row = dt*16 + q16;
        int off = row*64 + ((E >> 3) ^ (row & 7))*8 + (E & 7);
        bf16x4 vf = *(const bf16x4*)(&Vtl[cur][off]);
        o[dt] = mfma16(pk.v2, vf, o[dt]);
      }
    }
    asm volatile("s_waitcnt vmcnt(0)" ::: "memory");
    __builtin_amdgcn_s_barrier();
  }
  float li0 = 1.f / __shfl(lrun, 4*g + 0, 64);
  float li1 = 1.f / __shfl(lrun, 4*g + 1, 64);
  float li2 = 1.f / __shfl(lrun, 4*g + 2, 64);
  float li3 = 1.f / __shfl(lrun, 4*g + 3, 64);
  #pragma unroll
  for (int r=0;r<4;r++) {
    float li = (r==0)?li0:(r==1)?li1:(r==2)?li2:li3;
    int q = qw + 4*g + r;
    #pragma unroll
    for (int dt=0;dt<4;dt++) {
      int d = dt*16 + q16;
      attnb[((size_t)(b*S_ + q))*D_ + h*DH_ + d] = f2bf(o[dt][r] * li);
    }
  }
}

// ---------------- output GEMM: out = attn @ Wo^T + bo ----------------
// 128x128 tile, BKO=64 swizzled LDS reads, 512 thr / 8 waves, 2-buffer
// pipeline; chunked XCD swizzle (256 blocks, 32/XCD: 4 A-panels + Wo < L2).
__global__ __launch_bounds__(512) void gemm_out(
    const ushort_t* __restrict__ Abf, const ushort_t* __restrict__ Bbf,
    const float* __restrict__ bias, float* __restrict__ out) {
  __shared__ __align__(16) ushort_t Al[2][128*BKO];
  __shared__ __align__(16) ushort_t Bl[2][128*BKO];
  int tid = threadIdx.x;
  int w = tid >> 6, lane = tid & 63;
  int g = lane >> 4, q16 = lane & 15;
  int wrow = (w >> 2) * 64, wcol = (w & 3) * 32;
  int bid = blockIdx.y * 8 + blockIdx.x;
  int swz = (bid & 7) * 32 + (bid >> 3);
  int m0 = (swz >> 3) * 128, n0 = (swz & 7) * 128;
  const int K = D_;
  const int nt = K / BKO;

  auto stageg = [&](int t, int buf) {
    int k0 = t * BKO;
    #pragma unroll
    for (int it = 0; it < 2; ++it) {
      int c = it*512 + tid;
      int row = c >> 3, scc = ((c & 7) ^ (row & 7)) * 8;
      gl_lds16(Abf + (size_t)(m0+row)*K + k0 + scc, &Al[buf][c*8]);
      gl_lds16(Bbf + (size_t)(n0+row)*K + k0 + scc, &Bl[buf][c*8]);
    }
  };

  f32x4 zero = {0.f,0.f,0.f,0.f};
  f32x4 acc[4][2];
  for (int i=0;i<4;i++) for (int j=0;j<2;j++) acc[i][j] = zero;

  stageg(0, 0);
  asm volatile("s_waitcnt vmcnt(0)" ::: "memory");
  __builtin_amdgcn_s_barrier();

  for (int t = 0; t < nt; ++t) {
    int cur = t & 1;
    if (t + 1 < nt) stageg(t + 1, cur ^ 1);
    #pragma unroll
    for (int kk = 0; kk < 2; ++kk) {
      bf16x8 af[4], bfr[2];
      #pragma unroll
      for (int i=0;i<4;i++) {
        int row = wrow + i*16 + q16;
        int slot = ((kk*4 + g) ^ (row & 7)) * 8;
        af[i] = *(const bf16x8*)(&Al[cur][row*BKO + slot]);
      }
      #pragma unroll
      for (int j=0;j<2;j++) {
        int row = wcol + j*16 + q16;
        int slot = ((kk*4 + g) ^ (row & 7)) * 8;
        bfr[j] = *(const bf16x8*)(&Bl[cur][row*BKO + slot]);
      }
      #pragma unroll
      for (int i=0;i<4;i++)
        #pragma unroll
        for (int j=0;j<2;j++)
          acc[i][j] = __builtin_amdgcn_mfma_f32_16x16x32_bf16(af[i], bfr[j], acc[i][j], 0, 0, 0);
    }
    asm volatile("s_waitcnt vmcnt(0)" ::: "memory");
    __builtin_amdgcn_s_barrier();
  }
  #pragma unroll
  for (int i=0;i<4;i++)
    #pragma unroll
    for (int j=0;j<2;j++)
      #pragma unroll
      for (int r=0;r<4;r++) {
        int gm = m0 + wrow + i*16 + g*4 + r;
        int gn = n0 + wcol + j*16 + q16;
        out[(size_t)gm*D_ + gn] = acc[i][j][r] + bias[gn];
      }
}

extern "C" void kernel_launch(void* const* d_in, const int* in_sizes, int n_in,
                              void* d_out, int out_size, void* d_ws, size_t ws_size,
                              hipStream_t stream) {
  const float* x  = (const float*)d_in[0];
  const float* Wi = (const float*)d_in[1];
  const float* bi = (const float*)d_in[2];
  const float* Wo = (const float*)d_in[3];
  const float* bo = (const float*)d_in[4];
  const int* causal = (const int*)d_in[5];
  float* out = (float*)d_out;

  ushort_t* xb   = (ushort_t*)d_ws;                       // 4096*1024 (reused as vtb)
  ushort_t* Wib  = xb  + (size_t)MTOT*D_;                 // 3072*1024
  ushort_t* Wob  = Wib + (size_t)NQKV*D_;                 // 1024*1024
  ushort_t* qbuf = Wob + (size_t)D_*D_;                   // 32*2048*64
  ushort_t* kbuf = qbuf + (size_t)B_*H_*S_*DH_;
  ushort_t* vbuf = kbuf + (size_t)B_*H_*S_*DH_;
  ushort_t* attnb = vbuf + (size_t)B_*H_*S_*DH_;          // 4096*1024
  ushort_t* vtb  = xb;  // xb dead after gemm_qkv; reuse for transposed V

  int ntot = CVN1 + CVN2 + CVN3;
  cvt_all<<<(ntot+255)/256, 256, 0, stream>>>(x, Wi, Wo, xb, Wib, Wob);

  gemm_qkv<<<dim3(NQKV/128, MTOT/128), 512, 0, stream>>>(xb, Wib, bi, qbuf, kbuf, vbuf);
  transpose_v<<<dim3(S_/64, B_*H_), 256, 0, stream>>>(vbuf, vtb);
  attn_fwd<<<1024, 256, 0, stream>>>(qbuf, kbuf, vtb, attnb, causal);
  gemm_out<<<dim3(D_/128, MTOT/128), 512, 0, stream>>>(attnb, Wob, bo, out);
}

// Round 22
// 106.324 us; speedup vs baseline: 1.2328x; 1.0269x over previous
//
#include <hip/hip_runtime.h>
#include <hip/hip_bf16.h>
#include <stdint.h>

#define B_    2
#define S_    2048
#define D_    1024
#define H_    16
#define DH_   64
#define MTOT  (B_*S_)     // 4096
#define NQKV  (3*D_)      // 3072

typedef __attribute__((ext_vector_type(8))) short  bf16x8;
typedef __attribute__((ext_vector_type(4))) short  bf16x4;
typedef __attribute__((ext_vector_type(4))) float  f32x4;
typedef __attribute__((ext_vector_type(8))) unsigned short u16x8;
typedef unsigned short ushort_t;

__device__ __forceinline__ ushort_t f2bf(float f) {
  union { float f; unsigned int i; } v; v.f = f;
  unsigned int r = v.i + 0x7FFF + ((v.i >> 16) & 1);
  return (ushort_t)(r >> 16);
}

__device__ __forceinline__ unsigned cvt_pk_bf16(float lo, float hi) {
  unsigned r;
  asm("v_cvt_pk_bf16_f32 %0, %1, %2" : "=v"(r) : "v"(lo), "v"(hi));
  return r;
}

__device__ __forceinline__ float fexp2(float x) {
  float r;
  asm("v_exp_f32 %0, %1" : "=v"(r) : "v"(x));
  return r;
}

// K=16 bf16 MFMA: builtin name differs across ROCm versions; chain with asm fallback.
#if __has_builtin(__builtin_amdgcn_mfma_f32_16x16x16_bf16)
__device__ __forceinline__ f32x4 mfma16(bf16x4 a, bf16x4 b, f32x4 c) {
  return __builtin_amdgcn_mfma_f32_16x16x16_bf16(a, b, c, 0, 0, 0);
}
#elif __has_builtin(__builtin_amdgcn_mfma_f32_16x16x16bf16_1k)
__device__ __forceinline__ f32x4 mfma16(bf16x4 a, bf16x4 b, f32x4 c) {
  return __builtin_amdgcn_mfma_f32_16x16x16bf16_1k(a, b, c, 0, 0, 0);
}
#else
__device__ __forceinline__ f32x4 mfma16(bf16x4 a, bf16x4 b, f32x4 c) {
  asm volatile("v_mfma_f32_16x16x16_bf16 %0, %1, %2, %0"
               : "+v"(c) : "v"(a), "v"(b));
  return c;
}
#endif

__device__ __forceinline__ void gl_lds16(const ushort_t* g, ushort_t* l) {
  __builtin_amdgcn_global_load_lds(
      (const __attribute__((address_space(1))) unsigned int*)g,
      (__attribute__((address_space(3))) unsigned int*)l, 16, 0, 0);
}

// ---------------- fused fp32 -> bf16 conversion (x, Wi, Wo) ----------------
#define CVN1 (MTOT*D_/8)
#define CVN2 (NQKV*D_/8)
#define CVN3 (D_*D_/8)
__global__ __launch_bounds__(256) void cvt_all(
    const float* __restrict__ x, const float* __restrict__ Wi, const float* __restrict__ Wo,
    ushort_t* __restrict__ xb, ushort_t* __restrict__ Wib, ushort_t* __restrict__ Wob) {
  int i = blockIdx.x * blockDim.x + threadIdx.x;
  const float* src; ushort_t* dst; int k;
  if (i < CVN1)            { src = x;  dst = xb;  k = i; }
  else if (i < CVN1+CVN2)  { src = Wi; dst = Wib; k = i - CVN1; }
  else                     { src = Wo; dst = Wob; k = i - CVN1 - CVN2; }
  const float4* s4 = (const float4*)src;
  float4 a = s4[2*k], b = s4[2*k+1];
  u16x8 o;
  o[0]=f2bf(a.x); o[1]=f2bf(a.y); o[2]=f2bf(a.z); o[3]=f2bf(a.w);
  o[4]=f2bf(b.x); o[5]=f2bf(b.y); o[6]=f2bf(b.z); o[7]=f2bf(b.w);
  ((u16x8*)dst)[k] = o;
}

// ---------------- QKV GEMM: qkv = x @ Wi^T + bi ----------------
// gemm_out structure: 512 thr / 8 waves (2Mx4N, 64x32/wave), BK=64 swizzled,
// 2-buffer raw-barrier pipeline; chunked XCD swizzle; q/k/v scatter epilogue.
#define BKO 64
// scale folded into q: 1/sqrt(64) * log2(e)  (exp2-domain softmax)
#define QSCALE 0.18033688011112042f
__global__ __launch_bounds__(512) void gemm_qkv(
    const ushort_t* __restrict__ Abf, const ushort_t* __restrict__ Bbf,
    const float* __restrict__ bias,
    ushort_t* __restrict__ qb, ushort_t* __restrict__ kb, ushort_t* __restrict__ vb) {
  __shared__ __align__(16) ushort_t Al[2][128*BKO];
  __shared__ __align__(16) ushort_t Bl[2][128*BKO];
  int tid = threadIdx.x;
  int w = tid >> 6, lane = tid & 63;
  int g = lane >> 4, q16 = lane & 15;
  int wrow = (w >> 2) * 64, wcol = (w & 3) * 32;
  int bid = blockIdx.y * 24 + blockIdx.x;
  int swz = (bid & 7) * 96 + (bid >> 3);
  int m0 = (swz / 24) * 128, n0 = (swz % 24) * 128;
  const int K = D_;
  const int nt = K / BKO;

  auto stageg = [&](int t, int buf) {
    int k0 = t * BKO;
    #pragma unroll
    for (int it = 0; it < 2; ++it) {
      int c = it*512 + tid;
      int row = c >> 3, scc = ((c & 7) ^ (row & 7)) * 8;
      gl_lds16(Abf + (size_t)(m0+row)*K + k0 + scc, &Al[buf][c*8]);
      gl_lds16(Bbf + (size_t)(n0+row)*K + k0 + scc, &Bl[buf][c*8]);
    }
  };

  f32x4 zero = {0.f,0.f,0.f,0.f};
  f32x4 acc[4][2];
  for (int i=0;i<4;i++) for (int j=0;j<2;j++) acc[i][j] = zero;

  stageg(0, 0);
  asm volatile("s_waitcnt vmcnt(0)" ::: "memory");
  __builtin_amdgcn_s_barrier();

  for (int t = 0; t < nt; ++t) {
    int cur = t & 1;
    if (t + 1 < nt) stageg(t + 1, cur ^ 1);
    #pragma unroll
    for (int kk = 0; kk < 2; ++kk) {
      bf16x8 af[4], bfr[2];
      #pragma unroll
      for (int i=0;i<4;i++) {
        int row = wrow + i*16 + q16;
        int slot = ((kk*4 + g) ^ (row & 7)) * 8;
        af[i] = *(const bf16x8*)(&Al[cur][row*BKO + slot]);
      }
      #pragma unroll
      for (int j=0;j<2;j++) {
        int row = wcol + j*16 + q16;
        int slot = ((kk*4 + g) ^ (row & 7)) * 8;
        bfr[j] = *(const bf16x8*)(&Bl[cur][row*BKO + slot]);
      }
      #pragma unroll
      for (int i=0;i<4;i++)
        #pragma unroll
        for (int j=0;j<2;j++)
          acc[i][j] = __builtin_amdgcn_mfma_f32_16x16x32_bf16(af[i], bfr[j], acc[i][j], 0, 0, 0);
    }
    asm volatile("s_waitcnt vmcnt(0)" ::: "memory");
    __builtin_amdgcn_s_barrier();
  }
  #pragma unroll
  for (int i=0;i<4;i++)
    #pragma unroll
    for (int j=0;j<2;j++)
      #pragma unroll
      for (int r=0;r<4;r++) {
        int gm = m0 + wrow + i*16 + g*4 + r;
        int gn = n0 + wcol + j*16 + q16;
        float v = acc[i][j][r] + bias[gn];
        int b = gm >> 11, s = gm & (S_-1);
        int sect = gn >> 10, hn = gn & (D_-1);
        int hh = hn >> 6, d = hn & 63;
        size_t idx = (((size_t)(b*H_ + hh))*S_ + s)*DH_ + d;
        if (sect == 0) v *= QSCALE;
        ushort_t val = f2bf(v);
        if (sect == 0) qb[idx] = val;
        else if (sect == 1) kb[idx] = val;
        else vb[idx] = val;
      }
}

// ---------------- V transpose: [BH][S][DH] -> [BH][DH][S] ----------------
__global__ __launch_bounds__(256) void transpose_v(
    const ushort_t* __restrict__ vb, ushort_t* __restrict__ vtb) {
  __shared__ ushort_t T[64*72];
  int bh = blockIdx.y;
  int s0 = blockIdx.x * 64;
  int tid = threadIdx.x;
  const ushort_t* src = vb + (size_t)bh * S_ * DH_;
  ushort_t* dst = vtb + (size_t)bh * DH_ * S_;
  for (int it = 0; it < 2; ++it) {
    int c = it*256 + tid;
    int row = c >> 3, cc = c & 7;
    *(uint4*)&T[row*72 + cc*8] = *(const uint4*)(src + (size_t)(s0+row)*DH_ + cc*8);
  }
  __syncthreads();
  for (int it = 0; it < 2; ++it) {
    int c = it*256 + tid;
    int d = c >> 3, sc = c & 7;
    u16x8 o;
    #pragma unroll
    for (int e = 0; e < 8; ++e) o[e] = T[(sc*8+e)*72 + d];
    *(u16x8*)(dst + (size_t)d*S_ + s0 + sc*8) = o;
  }
}

// ---------------- flash attention v13: lazy max + deferred sum ----------------
// v12 + per-lane partial lrun (NO cross-lane reduce in the loop; one xor16+
// xor32 reduce at epilogue). mrun stays uniform across each q-row's 4-lane
// group (rescale path reduces globally), so partials scale consistently.
// Inner loop now has ZERO serial shuffles (only the __all vote, SALU).
#define KVB 64
#define DTHR 8.0f
__global__ __launch_bounds__(256) void attn_fwd(
    const ushort_t* __restrict__ qb, const ushort_t* __restrict__ kb,
    const ushort_t* __restrict__ vtb, ushort_t* __restrict__ attnb,
    const int* __restrict__ causal) {
  int wg = blockIdx.x;                  // 0..1023
  int xcd = wg & 7;
  int j = wg >> 3;                      // 0..127 per-XCD dispatch sequence
  int v = j >> 5;                       // visit 0..3
  int u = j & 31;                       // CU slot within XCD
  int a = u >> 2;                       // qblk subgroup 0..7
  int qi = v*8 + ((v & 1) ? (7 - a) : a);   // boustrophedon: per-CU sums equal
  int qblk = 31 - qi;
  int bh = (u & 3) * 8 + xcd;           // 4 bh per XCD -> KV L2-resident
  int b = bh >> 4, h = bh & 15;
  int tid = threadIdx.x, w = tid >> 6, lane = tid & 63;
  int g = lane >> 4, q16 = lane & 15;
  const ushort_t* qh  = qb  + (size_t)bh * S_ * DH_;
  const ushort_t* kh  = kb  + (size_t)bh * S_ * DH_;
  const ushort_t* vth = vtb + (size_t)bh * DH_ * S_;
  __shared__ __align__(16) ushort_t Kl[2][KVB*64];
  __shared__ __align__(16) ushort_t Vtl[2][64*KVB];
  bool use_causal = (causal[0] != 0);

  int nkv = use_causal ? (qblk + 1) : (S_/KVB);
  int qw = qblk*64 + w*16;

  bf16x8 qc0 = *(const bf16x8*)(qh + (size_t)(qw + q16)*DH_ +  0 + g*8);
  bf16x8 qc1 = *(const bf16x8*)(qh + (size_t)(qw + q16)*DH_ + 32 + g*8);

  int c0 = tid, c1 = tid + 256;
  int r0 = c0 >> 3, sw0 = ((c0 & 7) ^ (r0 & 7)) * 8;
  int r1 = c1 >> 3, sw1 = ((c1 & 7) ^ (r1 & 7)) * 8;
  const ushort_t* kp0 = kh + r0*DH_ + sw0;
  const ushort_t* kp1 = kh + r1*DH_ + sw1;
  const ushort_t* vp0 = vth + (size_t)r0*S_ + sw0;
  const ushort_t* vp1 = vth + (size_t)r1*S_ + sw1;

  auto stage = [&](int t, int buf) {
    size_t kadv = (size_t)(t*KVB) * DH_;
    int vadv = t*KVB;
    gl_lds16(kp0 + kadv, &Kl[buf][c0*8]);
    gl_lds16(kp1 + kadv, &Kl[buf][c1*8]);
    gl_lds16(vp0 + vadv, &Vtl[buf][c0*8]);
    gl_lds16(vp1 + vadv, &Vtl[buf][c1*8]);
  };

  f32x4 zero = {0.f,0.f,0.f,0.f};
  f32x4 o[4];
  #pragma unroll
  for (int dt=0;dt<4;dt++) o[dt] = zero;
  float mrun = -1e30f, lrun = 0.f;   // lrun: PER-LANE partial row sum

  stage(0, 0);
  asm volatile("s_waitcnt vmcnt(0)" ::: "memory");
  __builtin_amdgcn_s_barrier();

  for (int it = 0; it < nkv; ++it) {
    int cur = it & 1;
    int kvbase = it * KVB;
    if (it + 1 < nkv) stage(it + 1, cur ^ 1);   // lands during compute below

    f32x4 sacc[4];
    #pragma unroll
    for (int j2=0;j2<4;j2++) sacc[j2] = zero;
    #pragma unroll
    for (int kk=0;kk<2;kk++) {
      bf16x8 qf = kk ? qc1 : qc0;
      #pragma unroll
      for (int j2=0;j2<4;j2++) {
        int row = j2*16 + q16;
        int slot = (kk*4 + g) ^ (row & 7);
        bf16x8 kf = *(const bf16x8*)(&Kl[cur][row*64 + slot*8]);
        sacc[j2] = __builtin_amdgcn_mfma_f32_16x16x32_bf16(kf, qf, sacc[j2], 0, 0, 0);
      }
    }
    if (use_causal && kvbase + KVB - 1 > qw) {
      int qd = qw + q16 - kvbase;
      #pragma unroll
      for (int j2=0;j2<4;j2++)
        #pragma unroll
        for (int r=0;r<4;r++)
          if (16*j2 + 4*g + r > qd) sacc[j2][r] = -1e30f;
    }
    // ---- lazy cross-lane max: shuffle-free defer test on local max ----
    float m0v = fmaxf(fmaxf(sacc[0][0], sacc[0][1]), fmaxf(sacc[0][2], sacc[0][3]));
    float m1v = fmaxf(fmaxf(sacc[1][0], sacc[1][1]), fmaxf(sacc[1][2], sacc[1][3]));
    float m2v = fmaxf(fmaxf(sacc[2][0], sacc[2][1]), fmaxf(sacc[2][2], sacc[2][3]));
    float m3v = fmaxf(fmaxf(sacc[3][0], sacc[3][1]), fmaxf(sacc[3][2], sacc[3][3]));
    float lmx = fmaxf(fmaxf(m0v, m1v), fmaxf(m2v, m3v));
    if (!__all(lmx - mrun <= DTHR)) {
      float mx = fmaxf(lmx, __shfl_xor(lmx, 16, 64));
      mx = fmaxf(mx, __shfl_xor(mx, 32, 64));
      float mnew = fmaxf(mrun, mx);
      float alpha = fexp2(mrun - mnew);
      lrun *= alpha;                      // per-lane partial scales uniformly
      float av0 = __shfl(alpha, 4*g + 0, 64);
      float av1 = __shfl(alpha, 4*g + 1, 64);
      float av2 = __shfl(alpha, 4*g + 2, 64);
      float av3 = __shfl(alpha, 4*g + 3, 64);
      #pragma unroll
      for (int dt=0;dt<4;dt++) {
        o[dt][0] *= av0; o[dt][1] *= av1; o[dt][2] *= av2; o[dt][3] *= av3;
      }
      mrun = mnew;
    }
    float p[4][4];
    float rs = 0.f;
    #pragma unroll
    for (int j2=0;j2<4;j2++)
      #pragma unroll
      for (int r=0;r<4;r++) {
        p[j2][r] = fexp2(sacc[j2][r] - mrun);
        rs += p[j2][r];
      }
    lrun += rs;                           // deferred: no cross-lane reduce here
    #pragma unroll
    for (int s=0;s<4;s++) {
      union { unsigned u2[2]; bf16x4 v2; } pk;
      pk.u2[0] = cvt_pk_bf16(p[s][0], p[s][1]);
      pk.u2[1] = cvt_pk_bf16(p[s][2], p[s][3]);
      int E = 16*s + 4*g;
      #pragma unroll
      for (int dt=0;dt<4;dt++) {
        int row = dt*16 + q16;
        int off = row*64 + ((E >> 3) ^ (row & 7))*8 + (E & 7);
        bf16x4 vf = *(const bf16x4*)(&Vtl[cur][off]);
        o[dt] = mfma16(pk.v2, vf, o[dt]);
      }
    }
    asm volatile("s_waitcnt vmcnt(0)" ::: "memory");
    __builtin_amdgcn_s_barrier();
  }
  // ---- epilogue: one-time cross-lane sum of the partials ----
  lrun += __shfl_xor(lrun, 16, 64);
  lrun += __shfl_xor(lrun, 32, 64);
  float li0 = 1.f / __shfl(lrun, 4*g + 0, 64);
  float li1 = 1.f / __shfl(lrun, 4*g + 1, 64);
  float li2 = 1.f / __shfl(lrun, 4*g + 2, 64);
  float li3 = 1.f / __shfl(lrun, 4*g + 3, 64);
  #pragma unroll
  for (int r=0;r<4;r++) {
    float li = (r==0)?li0:(r==1)?li1:(r==2)?li2:li3;
    int q = qw + 4*g + r;
    #pragma unroll
    for (int dt=0;dt<4;dt++) {
      int d = dt*16 + q16;
      attnb[((size_t)(b*S_ + q))*D_ + h*DH_ + d] = f2bf(o[dt][r] * li);
    }
  }
}

// ---------------- output GEMM: out = attn @ Wo^T + bo ----------------
// 128x128 tile, BKO=64 swizzled LDS reads, 512 thr / 8 waves, 2-buffer
// pipeline; chunked XCD swizzle (256 blocks, 32/XCD: 4 A-panels + Wo < L2).
__global__ __launch_bounds__(512) void gemm_out(
    const ushort_t* __restrict__ Abf, const ushort_t* __restrict__ Bbf,
    const float* __restrict__ bias, float* __restrict__ out) {
  __shared__ __align__(16) ushort_t Al[2][128*BKO];
  __shared__ __align__(16) ushort_t Bl[2][128*BKO];
  int tid = threadIdx.x;
  int w = tid >> 6, lane = tid & 63;
  int g = lane >> 4, q16 = lane & 15;
  int wrow = (w >> 2) * 64, wcol = (w & 3) * 32;
  int bid = blockIdx.y * 8 + blockIdx.x;
  int swz = (bid & 7) * 32 + (bid >> 3);
  int m0 = (swz >> 3) * 128, n0 = (swz & 7) * 128;
  const int K = D_;
  const int nt = K / BKO;

  auto stageg = [&](int t, int buf) {
    int k0 = t * BKO;
    #pragma unroll
    for (int it = 0; it < 2; ++it) {
      int c = it*512 + tid;
      int row = c >> 3, scc = ((c & 7) ^ (row & 7)) * 8;
      gl_lds16(Abf + (size_t)(m0+row)*K + k0 + scc, &Al[buf][c*8]);
      gl_lds16(Bbf + (size_t)(n0+row)*K + k0 + scc, &Bl[buf][c*8]);
    }
  };

  f32x4 zero = {0.f,0.f,0.f,0.f};
  f32x4 acc[4][2];
  for (int i=0;i<4;i++) for (int j=0;j<2;j++) acc[i][j] = zero;

  stageg(0, 0);
  asm volatile("s_waitcnt vmcnt(0)" ::: "memory");
  __builtin_amdgcn_s_barrier();

  for (int t = 0; t < nt; ++t) {
    int cur = t & 1;
    if (t + 1 < nt) stageg(t + 1, cur ^ 1);
    #pragma unroll
    for (int kk = 0; kk < 2; ++kk) {
      bf16x8 af[4], bfr[2];
      #pragma unroll
      for (int i=0;i<4;i++) {
        int row = wrow + i*16 + q16;
        int slot = ((kk*4 + g) ^ (row & 7)) * 8;
        af[i] = *(const bf16x8*)(&Al[cur][row*BKO + slot]);
      }
      #pragma unroll
      for (int j=0;j<2;j++) {
        int row = wcol + j*16 + q16;
        int slot = ((kk*4 + g) ^ (row & 7)) * 8;
        bfr[j] = *(const bf16x8*)(&Bl[cur][row*BKO + slot]);
      }
      #pragma unroll
      for (int i=0;i<4;i++)
        #pragma unroll
        for (int j=0;j<2;j++)
          acc[i][j] = __builtin_amdgcn_mfma_f32_16x16x32_bf16(af[i], bfr[j], acc[i][j], 0, 0, 0);
    }
    asm volatile("s_waitcnt vmcnt(0)" ::: "memory");
    __builtin_amdgcn_s_barrier();
  }
  #pragma unroll
  for (int i=0;i<4;i++)
    #pragma unroll
    for (int j=0;j<2;j++)
      #pragma unroll
      for (int r=0;r<4;r++) {
        int gm = m0 + wrow + i*16 + g*4 + r;
        int gn = n0 + wcol + j*16 + q16;
        out[(size_t)gm*D_ + gn] = acc[i][j][r] + bias[gn];
      }
}

extern "C" void kernel_launch(void* const* d_in, const int* in_sizes, int n_in,
                              void* d_out, int out_size, void* d_ws, size_t ws_size,
                              hipStream_t stream) {
  const float* x  = (const float*)d_in[0];
  const float* Wi = (const float*)d_in[1];
  const float* bi = (const float*)d_in[2];
  const float* Wo = (const float*)d_in[3];
  const float* bo = (const float*)d_in[4];
  const int* causal = (const int*)d_in[5];
  float* out = (float*)d_out;

  ushort_t* xb   = (ushort_t*)d_ws;                       // 4096*1024 (reused as vtb)
  ushort_t* Wib  = xb  + (size_t)MTOT*D_;                 // 3072*1024
  ushort_t* Wob  = Wib + (size_t)NQKV*D_;                 // 1024*1024
  ushort_t* qbuf = Wob + (size_t)D_*D_;                   // 32*2048*64
  ushort_t* kbuf = qbuf + (size_t)B_*H_*S_*DH_;
  ushort_t* vbuf = kbuf + (size_t)B_*H_*S_*DH_;
  ushort_t* attnb = vbuf + (size_t)B_*H_*S_*DH_;          // 4096*1024
  ushort_t* vtb  = xb;  // xb dead after gemm_qkv; reuse for transposed V

  int ntot = CVN1 + CVN2 + CVN3;
  cvt_all<<<(ntot+255)/256, 256, 0, stream>>>(x, Wi, Wo, xb, Wib, Wob);

  gemm_qkv<<<dim3(NQKV/128, MTOT/128), 512, 0, stream>>>(xb, Wib, bi, qbuf, kbuf, vbuf);
  transpose_v<<<dim3(S_/64, B_*H_), 256, 0, stream>>>(vbuf, vtb);
  attn_fwd<<<1024, 256, 0, stream>>>(qbuf, kbuf, vtb, attnb, causal);
  gemm_out<<<dim3(D_/128, MTOT/128), 512, 0, stream>>>(attnb, Wob, bo, out);
}